// Round 9
// baseline (563.092 us; speedup 1.0000x reference)
//
#include <hip/hip_runtime.h>

#define N_FUNC 200000
#define N_API  50000
#define H      64
#define NLAYERS 2
#define SCAN_CHUNK 2048
#define NBF 3125   // N_FUNC/64 exact
#define NBA 782    // ceil(N_API/64)
#define PREP_BLOCKS 208  // ceil(53248/256)
#define NSHADOW 64

typedef unsigned short u16;

__device__ __forceinline__ void fma4(float4& a, float s, float4 w) {
    a.x = fmaf(s, w.x, a.x); a.y = fmaf(s, w.y, a.y);
    a.z = fmaf(s, w.z, a.z); a.w = fmaf(s, w.w, a.w);
}
__device__ __forceinline__ void add4(float4& a, float4 v) {
    a.x += v.x; a.y += v.y; a.z += v.z; a.w += v.w;
}
__device__ __forceinline__ void scl4(float4& a, float s) {
    a.x *= s; a.y *= s; a.z *= s; a.w *= s;
}
__device__ __forceinline__ float bf2f(u16 u) {
    return __uint_as_float(((unsigned int)u) << 16);
}
__device__ __forceinline__ u16 f2bf(float f) {   // round-to-nearest-even
    unsigned int x = __float_as_uint(f);
    return (u16)((x + 0x7FFFu + ((x >> 16) & 1u)) >> 16);
}
__device__ __forceinline__ float4 b2f4(ushort4 v) {
    return make_float4(bf2f(v.x), bf2f(v.y), bf2f(v.z), bf2f(v.w));
}
__device__ __forceinline__ ushort4 f2b4(float4 o) {
    ushort4 r; r.x = f2bf(o.x); r.y = f2bf(o.y); r.z = f2bf(o.z); r.w = f2bf(o.w);
    return r;
}
__device__ __forceinline__ void addb(float4& a, ushort4 v) {
    a.x += bf2f(v.x); a.y += bf2f(v.y); a.z += bf2f(v.z); a.w += bf2f(v.w);
}

// ---- K1: weight prep (208 blocks) + edge histogram (rest) in one launch ----
__global__ __launch_bounds__(256) void prep_and_count(
        const float* __restrict__ w_in_func, const float* __restrict__ w_in_api,
        const float* __restrict__ Wl_calls, const float* __restrict__ Wr_calls,
        const float* __restrict__ Wl_uses,  const float* __restrict__ Wr_uses,
        const float* __restrict__ Wl_usedby,const float* __restrict__ Wr_usedby,
        float* __restrict__ out,
        const int* __restrict__ dC, const int* __restrict__ dU, const int* __restrict__ dA,
        int* __restrict__ cC, int* __restrict__ cU, int* __restrict__ cA, int E)
{
    int b = blockIdx.x;
    if (b < PREP_BLOCKS) {
        int idx = b * 256 + threadIdx.x;
        if (idx < 8192) {
            int k = idx >> 6, o = idx & 63;
            out[idx] = w_in_func[o * 128 + k];
        } else if (idx < 12288) {
            int r = idx - 8192; int k = r >> 6, o = r & 63;
            out[idx] = w_in_api[o * 64 + k];
        } else if (idx < 12288 + 10 * 4096) {
            int r = idx - 12288;
            int m = r >> 12, w = r & 4095;
            int k = w >> 6, o = w & 63;
            int l = m / 5, which = m - 5 * l;
            const float* A; const float* B = nullptr;
            if (which == 0)      { A = Wr_calls  + l * 4096; B = Wr_usedby + l * 4096; }
            else if (which == 1)   A = Wl_calls  + l * 4096;
            else if (which == 2)   A = Wl_usedby + l * 4096;
            else if (which == 3)   A = Wl_uses   + l * 4096;
            else                   A = Wr_uses   + l * 4096;
            float v = A[o * 64 + k];
            if (B) v += B[o * 64 + k];
            out[idx] = v;
        }
    } else {
        int i = (b - PREP_BLOCKS) * 256 + threadIdx.x;
        if (i >= 3 * E) return;
        int rel = i / E, e = i - rel * E;
        if (rel == 0)      atomicAdd(&cC[dC[e]], 1);
        else if (rel == 1) atomicAdd(&cU[dU[e]], 1);
        else               atomicAdd(&cA[dA[e]], 1);
    }
}

__global__ __launch_bounds__(256) void block_sums_all(
        const int* __restrict__ cC, const int* __restrict__ cU, const int* __restrict__ cA,
        int* __restrict__ pC, int* __restrict__ pU, int* __restrict__ pA,
        int nF, int nA, int nbF)
{
    __shared__ int sd[256];
    int b = blockIdx.x, t = threadIdx.x;
    const int* cnt; int* part; int n, lb;
    if (b < nbF)            { cnt = cC; part = pC; n = nF; lb = b; }
    else if (b < 2 * nbF)   { cnt = cU; part = pU; n = nF; lb = b - nbF; }
    else                    { cnt = cA; part = pA; n = nA; lb = b - 2 * nbF; }
    int base = lb * SCAN_CHUNK;
    int s = 0;
    for (int i = t; i < SCAN_CHUNK; i += 256) {
        int idx = base + i;
        s += (idx < n) ? cnt[idx] : 0;
    }
    sd[t] = s; __syncthreads();
    for (int st = 128; st > 0; st >>= 1) {
        if (t < st) sd[t] += sd[t + st];
        __syncthreads();
    }
    if (t == 0) part[lb] = sd[0];
}

__global__ __launch_bounds__(192) void scan_small_all(int* pC, int* pU, int* pA, int nbF, int nbA)
{
    int w = threadIdx.x >> 6, lane = threadIdx.x & 63;
    int* p = (w == 0) ? pC : (w == 1) ? pU : pA;
    int nb = (w == 2) ? nbA : nbF;
    int o0 = (lane < nb) ? p[lane] : 0;
    int o1 = (64 + lane < nb) ? p[64 + lane] : 0;
    int v0 = o0, v1 = o1;
    for (int off = 1; off < 64; off <<= 1) {
        int x0 = __shfl_up(v0, off);
        int x1 = __shfl_up(v1, off);
        if (lane >= off) { v0 += x0; v1 += x1; }
    }
    int tot0 = __shfl(v0, 63);
    if (lane < nb) p[lane] = v0 - o0;
    if (64 + lane < nb) p[64 + lane] = tot0 + v1 - o1;
}

__global__ __launch_bounds__(256) void write_rowptr_all(
        const int* __restrict__ cC, const int* __restrict__ cU, const int* __restrict__ cA,
        const int* __restrict__ pC, const int* __restrict__ pU, const int* __restrict__ pA,
        int* __restrict__ rpC, int* __restrict__ rpU, int* __restrict__ rpA,
        int* __restrict__ nxC, int* __restrict__ nxU, int* __restrict__ nxA,
        int nF, int nA, int nbF, int E)
{
    __shared__ int sc[256];
    int b = blockIdx.x, t = threadIdx.x;
    const int* cnt; const int* part; int* rp; int* nx; int n, lb;
    if (b < nbF)            { cnt = cC; part = pC; rp = rpC; nx = nxC; n = nF; lb = b; }
    else if (b < 2 * nbF)   { cnt = cU; part = pU; rp = rpU; nx = nxU; n = nF; lb = b - nbF; }
    else                    { cnt = cA; part = pA; rp = rpA; nx = nxA; n = nA; lb = b - 2 * nbF; }
    int base = lb * SCAN_CHUNK;
    int loc[8]; int s = 0;
    #pragma unroll
    for (int i = 0; i < 8; ++i) {
        int idx = base + t * 8 + i;
        int v = (idx < n) ? cnt[idx] : 0;
        loc[i] = s; s += v;
    }
    sc[t] = s; __syncthreads();
    for (int st = 1; st < 256; st <<= 1) {
        int v = (t >= st) ? sc[t - st] : 0;
        __syncthreads();
        sc[t] += v;
        __syncthreads();
    }
    int off = part[lb] + (t > 0 ? sc[t - 1] : 0);
    #pragma unroll
    for (int i = 0; i < 8; ++i) {
        int idx = base + t * 8 + i;
        if (idx < n) { int v = off + loc[i]; rp[idx] = v; nx[idx] = v; }
    }
    if (lb == 0 && t == 0) rp[n] = E;
}

// ---- shared GEMM-accumulate over a 64x64 LDS tile (XOR-swizzled) ----
__device__ __forceinline__ void gemm_acc(const float4* X, const float4* __restrict__ wt4,
        int og, int ng, float4 acc[4])
{
    for (int k4 = 0; k4 < 16; ++k4) {
        float4 w0 = wt4[(4 * k4 + 0) * 16 + og];
        float4 w1 = wt4[(4 * k4 + 1) * 16 + og];
        float4 w2 = wt4[(4 * k4 + 2) * 16 + og];
        float4 w3 = wt4[(4 * k4 + 3) * 16 + og];
        #pragma unroll
        for (int j = 0; j < 4; ++j) {
            int n = ng * 4 + j;
            float4 xv = X[n * 16 + (k4 ^ ((n >> 2) & 7))];
            fma4(acc[j], xv.x, w0); fma4(acc[j], xv.y, w1);
            fma4(acc[j], xv.z, w2); fma4(acc[j], xv.w, w3);
        }
    }
}

// ---- proj bodies (16KB LDS); h output in bf16 ----
__device__ __forceinline__ void proj_body128(const float* __restrict__ x,
        const float* __restrict__ wt, const float* __restrict__ bias,
        u16* __restrict__ hout, int i0, float4* smem)
{
    const int t = threadIdx.x;
    const int og = t & 15, ng = t >> 4;
    float4 acc[4];
    #pragma unroll
    for (int j = 0; j < 4; ++j) acc[j] = make_float4(0.f, 0.f, 0.f, 0.f);
    const float4* w4 = reinterpret_cast<const float4*>(wt);
    #pragma unroll
    for (int ph = 0; ph < 2; ++ph) {
        if (ph) __syncthreads();
        for (int idx = t; idx < 1024; idx += 256) {
            int n = idx >> 4, k4 = idx & 15;
            smem[n * 16 + (k4 ^ ((n >> 2) & 7))] =
                *reinterpret_cast<const float4*>(x + (size_t)(i0 + n) * 128 + ph * 64 + k4 * 4);
        }
        __syncthreads();
        gemm_acc(smem, w4 + ph * 1024, og, ng, acc);
    }
    float4 b = reinterpret_cast<const float4*>(bias)[og];
    #pragma unroll
    for (int j = 0; j < 4; ++j) {
        int node = i0 + ng * 4 + j;
        float4 o;
        o.x = fmaxf(acc[j].x + b.x, 0.f);
        o.y = fmaxf(acc[j].y + b.y, 0.f);
        o.z = fmaxf(acc[j].z + b.z, 0.f);
        o.w = fmaxf(acc[j].w + b.w, 0.f);
        *reinterpret_cast<ushort4*>(hout + (size_t)node * H + og * 4) = f2b4(o);
    }
}

__device__ __forceinline__ void proj_body64(const float* __restrict__ x,
        const float* __restrict__ wt, const float* __restrict__ bias,
        u16* __restrict__ hout, int i0, int nN, float4* smem)
{
    const int t = threadIdx.x;
    for (int idx = t; idx < 1024; idx += 256) {
        int n = idx >> 4, k4 = idx & 15;
        float4 v = make_float4(0.f, 0.f, 0.f, 0.f);
        if (i0 + n < nN)
            v = *reinterpret_cast<const float4*>(x + (size_t)(i0 + n) * 64 + k4 * 4);
        smem[n * 16 + (k4 ^ ((n >> 2) & 7))] = v;
    }
    __syncthreads();
    const int og = t & 15, ng = t >> 4;
    float4 acc[4];
    #pragma unroll
    for (int j = 0; j < 4; ++j) acc[j] = make_float4(0.f, 0.f, 0.f, 0.f);
    gemm_acc(smem, reinterpret_cast<const float4*>(wt), og, ng, acc);
    float4 b = reinterpret_cast<const float4*>(bias)[og];
    #pragma unroll
    for (int j = 0; j < 4; ++j) {
        int node = i0 + ng * 4 + j;
        if (node < nN) {
            float4 o;
            o.x = fmaxf(acc[j].x + b.x, 0.f);
            o.y = fmaxf(acc[j].y + b.y, 0.f);
            o.z = fmaxf(acc[j].z + b.z, 0.f);
            o.w = fmaxf(acc[j].w + b.w, 0.f);
            *reinterpret_cast<ushort4*>(hout + (size_t)node * H + og * 4) = f2b4(o);
        }
    }
}

// ---- K5: CSR fill + both projections, 16KB LDS ----
__global__ __launch_bounds__(256, 8) void fill_and_proj(
        const int* __restrict__ sC, const int* __restrict__ dC,
        const int* __restrict__ sU, const int* __restrict__ dU,
        const int* __restrict__ sA, const int* __restrict__ dA,
        int* __restrict__ nxC, int* __restrict__ nxU, int* __restrict__ nxA,
        int* __restrict__ colC, int* __restrict__ colU, int* __restrict__ colA, int E,
        int fillB,
        const float* __restrict__ xf, const float* __restrict__ wtf,
        const float* __restrict__ bf, u16* __restrict__ hf,
        const float* __restrict__ xa, const float* __restrict__ wta,
        const float* __restrict__ ba, u16* __restrict__ ha)
{
    __shared__ __align__(16) float4 smem[64 * 16];
    int b = blockIdx.x;
    if (b < fillB) {
        int i = b * 256 + threadIdx.x;
        if (i >= 3 * E) return;
        int rel = i / E, e = i - rel * E;
        if (rel == 0)      { int pos = atomicAdd(&nxC[dC[e]], 1); colC[pos] = sC[e]; }
        else if (rel == 1) { int pos = atomicAdd(&nxU[dU[e]], 1); colU[pos] = sU[e]; }
        else               { int pos = atomicAdd(&nxA[dA[e]], 1); colA[pos] = sA[e]; }
    } else {
        int b2 = b - fillB;
        if (b2 < NBF) proj_body128(xf, wtf, bf, hf, b2 * 64, smem);
        else          proj_body64(xa, wta, ba, ha, (b2 - NBF) * 64, N_API, smem);
    }
}

// ---- 8-deep interleaved CSR gather on bf16 rows (8B per lane) ----
__device__ __forceinline__ void gather8(const u16* __restrict__ src,
        const int* __restrict__ col, int j[4], const int e[4], int L, float4 a[4])
{
    while (j[0] < e[0] || j[1] < e[1] || j[2] < e[2] || j[3] < e[3]) {
        ushort4 v[8]; bool act[8];
        #pragma unroll
        for (int p = 0; p < 4; ++p) {
            int jj = j[p];
            act[2 * p]     = jj < e[p];
            act[2 * p + 1] = jj + 1 < e[p];
            if (act[2 * p]) {
                int s = col[jj];
                v[2 * p] = *reinterpret_cast<const ushort4*>(src + (size_t)s * H + L * 4);
            }
            if (act[2 * p + 1]) {
                int s = col[jj + 1];
                v[2 * p + 1] = *reinterpret_cast<const ushort4*>(src + (size_t)s * H + L * 4);
            }
            j[p] = jj + 2;
        }
        #pragma unroll
        for (int q = 0; q < 8; ++q) if (act[q]) addb(a[q >> 1], v[q]);
    }
}

// ---- fused layer: bf16 h in/out, fp32 compute; optional fused mean-pool ----
__global__ __launch_bounds__(256, 4) void layer_both(
        const u16* __restrict__ hf_old, const u16* __restrict__ ha_old,
        u16* __restrict__ hf_new, u16* __restrict__ ha_new,
        const int* __restrict__ rpC, const int* __restrict__ colC,
        const int* __restrict__ rpU, const int* __restrict__ colU,
        const int* __restrict__ rpA, const int* __restrict__ colA,
        const float* __restrict__ wtr, const float* __restrict__ wtlc,
        const float* __restrict__ wtlu,
        const float* __restrict__ wtruse, const float* __restrict__ wtluse,
        const float* __restrict__ bias_c, const float* __restrict__ bias_u,
        const float* __restrict__ bias_a,
        float* __restrict__ psh)   // nullptr for layer 0; else [NSHADOW][128] shadow sums
{
    __shared__ __align__(16) float4 X[64 * 16];    // 16 KB, reused across phases
    const int b = blockIdx.x;
    const int t = threadIdx.x;
    const int L = t & 15, g = t >> 4;
    const int og = t & 15, ng = t >> 4;
    const float4 z4 = make_float4(0.f, 0.f, 0.f, 0.f);

    float4 acc[4];
    #pragma unroll
    for (int j = 0; j < 4; ++j) acc[j] = z4;
    float4 o4[4];
    #pragma unroll
    for (int j = 0; j < 4; ++j) o4[j] = z4;

    if (b < NBF) {
        const int i0 = b * 64;
        // ---- Phase 1: mean over calls (hf_old) -> GEMM Wlc ----
        {
            int j1[4], e1[4], d1[4]; float4 a1[4];
            #pragma unroll
            for (int p = 0; p < 4; ++p) {
                int node = i0 + p * 16 + g;
                j1[p] = rpC[node]; e1[p] = rpC[node + 1]; d1[p] = e1[p] - j1[p];
                a1[p] = z4;
            }
            gather8(hf_old, colC, j1, e1, L, a1);
            #pragma unroll
            for (int p = 0; p < 4; ++p) {
                int n = p * 16 + g;
                scl4(a1[p], 1.0f / (float)max(d1[p], 1));
                X[n * 16 + (L ^ ((n >> 2) & 7))] = a1[p];
            }
        }
        __syncthreads();
        gemm_acc(X, reinterpret_cast<const float4*>(wtlc), og, ng, acc);
        __syncthreads();
        // ---- Phase 2: mean over usedby (ha_old) -> GEMM Wlu ----
        {
            int j2[4], e2[4], d2[4]; float4 a2[4];
            #pragma unroll
            for (int p = 0; p < 4; ++p) {
                int node = i0 + p * 16 + g;
                j2[p] = rpU[node]; e2[p] = rpU[node + 1]; d2[p] = e2[p] - j2[p];
                a2[p] = z4;
            }
            gather8(ha_old, colU, j2, e2, L, a2);
            #pragma unroll
            for (int p = 0; p < 4; ++p) {
                int n = p * 16 + g;
                scl4(a2[p], 1.0f / (float)max(d2[p], 1));
                X[n * 16 + (L ^ ((n >> 2) & 7))] = a2[p];
            }
        }
        __syncthreads();
        // ---- pre-issue phase-3 own rows (bf16, 8B/lane) ----
        ushort4 ow[4];
        #pragma unroll
        for (int r = 0; r < 4; ++r) {
            int idx = t + r * 256;
            int n = idx >> 4, k4 = idx & 15;
            ow[r] = *reinterpret_cast<const ushort4*>(hf_old + (size_t)(i0 + n) * H + k4 * 4);
        }
        gemm_acc(X, reinterpret_cast<const float4*>(wtlu), og, ng, acc);
        __syncthreads();
        #pragma unroll
        for (int r = 0; r < 4; ++r) {
            int idx = t + r * 256;
            int n = idx >> 4, k4 = idx & 15;
            X[n * 16 + (k4 ^ ((n >> 2) & 7))] = b2f4(ow[r]);
        }
        __syncthreads();
        gemm_acc(X, reinterpret_cast<const float4*>(wtr), og, ng, acc);
        // ---- epilogue ----
        float4 ba = reinterpret_cast<const float4*>(bias_c)[og];
        float4 bb = reinterpret_cast<const float4*>(bias_u)[og];
        float4 bv = make_float4(ba.x + bb.x, ba.y + bb.y, ba.z + bb.z, ba.w + bb.w);
        #pragma unroll
        for (int j = 0; j < 4; ++j) {
            int node = i0 + ng * 4 + j;
            float4 o;
            o.x = fmaxf(acc[j].x + bv.x, 0.f);
            o.y = fmaxf(acc[j].y + bv.y, 0.f);
            o.z = fmaxf(acc[j].z + bv.z, 0.f);
            o.w = fmaxf(acc[j].w + bv.w, 0.f);
            o4[j] = o;
            *reinterpret_cast<ushort4*>(hf_new + (size_t)node * H + og * 4) = f2b4(o);
        }
        if (psh) {
            float4 s = z4;
            #pragma unroll
            for (int j = 0; j < 4; ++j) add4(s, o4[j]);
            __syncthreads();             // X reads done; safe to reuse
            X[ng * 16 + og] = s;
            __syncthreads();
            if (ng == 0) {
                float4 tot = z4;
                #pragma unroll
                for (int q = 0; q < 16; ++q) add4(tot, X[q * 16 + og]);
                float* dst = psh + (size_t)(b & (NSHADOW - 1)) * 128 + og * 4;
                atomicAdd(dst + 0, tot.x); atomicAdd(dst + 1, tot.y);
                atomicAdd(dst + 2, tot.z); atomicAdd(dst + 3, tot.w);
            }
        }
    } else {
        const int i0 = (b - NBF) * 64;
        // ---- Phase 1: mean over uses (hf_old) -> GEMM Wluse ----
        {
            int j1[4], e1[4], d1[4]; float4 a1[4];
            #pragma unroll
            for (int p = 0; p < 4; ++p) {
                int node = i0 + p * 16 + g;
                if (node < N_API) { j1[p] = rpA[node]; e1[p] = rpA[node + 1]; }
                else { j1[p] = 0; e1[p] = 0; }
                d1[p] = e1[p] - j1[p];
                a1[p] = z4;
            }
            gather8(hf_old, colA, j1, e1, L, a1);
            #pragma unroll
            for (int p = 0; p < 4; ++p) {
                int n = p * 16 + g;
                scl4(a1[p], 1.0f / (float)max(d1[p], 1));
                X[n * 16 + (L ^ ((n >> 2) & 7))] = a1[p];
            }
        }
        __syncthreads();
        // ---- pre-issue own rows ----
        ushort4 ow[4];
        #pragma unroll
        for (int r = 0; r < 4; ++r) {
            int idx = t + r * 256;
            int n = idx >> 4, k4 = idx & 15;
            int node = i0 + n;
            ow[r] = make_ushort4(0, 0, 0, 0);
            if (node < N_API)
                ow[r] = *reinterpret_cast<const ushort4*>(ha_old + (size_t)node * H + k4 * 4);
        }
        gemm_acc(X, reinterpret_cast<const float4*>(wtluse), og, ng, acc);
        __syncthreads();
        #pragma unroll
        for (int r = 0; r < 4; ++r) {
            int idx = t + r * 256;
            int n = idx >> 4, k4 = idx & 15;
            X[n * 16 + (k4 ^ ((n >> 2) & 7))] = b2f4(ow[r]);
        }
        __syncthreads();
        gemm_acc(X, reinterpret_cast<const float4*>(wtruse), og, ng, acc);
        float4 bv = reinterpret_cast<const float4*>(bias_a)[og];
        #pragma unroll
        for (int j = 0; j < 4; ++j) {
            int node = i0 + ng * 4 + j;
            if (node < N_API) {
                float4 o;
                o.x = fmaxf(acc[j].x + bv.x, 0.f);
                o.y = fmaxf(acc[j].y + bv.y, 0.f);
                o.z = fmaxf(acc[j].z + bv.z, 0.f);
                o.w = fmaxf(acc[j].w + bv.w, 0.f);
                o4[j] = o;
                *reinterpret_cast<ushort4*>(ha_new + (size_t)node * H + og * 4) = f2b4(o);
            }
        }
        if (psh) {
            float4 s = z4;
            #pragma unroll
            for (int j = 0; j < 4; ++j) add4(s, o4[j]);
            __syncthreads();
            X[ng * 16 + og] = s;
            __syncthreads();
            if (ng == 0) {
                float4 tot = z4;
                #pragma unroll
                for (int q = 0; q < 16; ++q) add4(tot, X[q * 16 + og]);
                float* dst = psh + (size_t)(b & (NSHADOW - 1)) * 128 + 64 + og * 4;
                atomicAdd(dst + 0, tot.x); atomicAdd(dst + 1, tot.y);
                atomicAdd(dst + 2, tot.z); atomicAdd(dst + 3, tot.w);
            }
        }
    }
}

__global__ __launch_bounds__(128) void classifier_kernel(const float* __restrict__ shadows,
        const float* __restrict__ Wc1, const float* __restrict__ bc1,
        const float* __restrict__ Wc2, const float* __restrict__ bc2,
        float* __restrict__ out)
{
    __shared__ float ps[128];
    __shared__ float z1[64];
    int t = threadIdx.x;
    float s = 0.f;
    for (int q = 0; q < NSHADOW; ++q) s += shadows[q * 128 + t];
    ps[t] = s * (t < 64 ? (1.0f / N_FUNC) : (1.0f / N_API));
    __syncthreads();
    if (t < 64) {
        float a = bc1[t];
        for (int k = 0; k < 128; ++k) a = fmaf(ps[k], Wc1[t * 128 + k], a);
        z1[t] = fmaxf(a, 0.f);
    }
    __syncthreads();
    if (t < 2) {
        float a = bc2[t];
        for (int j = 0; j < 64; ++j) a = fmaf(z1[j], Wc2[t * 64 + j], a);
        out[t] = a;
    }
}

extern "C" void kernel_launch(void* const* d_in, const int* in_sizes, int n_in,
                              void* d_out, int out_size, void* d_ws, size_t ws_size,
                              hipStream_t stream)
{
    const float* x_func    = (const float*)d_in[0];
    const float* x_api     = (const float*)d_in[1];
    const float* w_in_func = (const float*)d_in[2];
    const float* b_in_func = (const float*)d_in[3];
    const float* w_in_api  = (const float*)d_in[4];
    const float* b_in_api  = (const float*)d_in[5];
    const float* Wl_calls  = (const float*)d_in[6];
    const float* bl_calls  = (const float*)d_in[7];
    const float* Wr_calls  = (const float*)d_in[8];
    const float* Wl_uses   = (const float*)d_in[9];
    const float* bl_uses   = (const float*)d_in[10];
    const float* Wr_uses   = (const float*)d_in[11];
    const float* Wl_usedby = (const float*)d_in[12];
    const float* bl_usedby = (const float*)d_in[13];
    const float* Wr_usedby = (const float*)d_in[14];
    const float* Wc1       = (const float*)d_in[15];
    const float* bc1       = (const float*)d_in[16];
    const float* Wc2       = (const float*)d_in[17];
    const float* bc2       = (const float*)d_in[18];
    const int*   ei_calls  = (const int*)d_in[19];
    const int*   ei_uses   = (const int*)d_in[20];
    const int*   ei_usedby = (const int*)d_in[21];
    const int E = in_sizes[19] / 2;

    float* ws = (float*)d_ws;
    size_t off = 0;
    u16* hf0 = (u16*)(ws + off); off += (size_t)N_FUNC * 32;  // bf16: 64 elems = 32 floats
    u16* hf1 = (u16*)(ws + off); off += (size_t)N_FUNC * 32;
    u16* ha0 = (u16*)(ws + off); off += (size_t)N_API * 32;
    u16* ha1 = (u16*)(ws + off); off += (size_t)N_API * 32;
    float* prep = ws + off; off += 12288 + 10 * 4096;
    int* cntC = (int*)(ws + off); off += N_FUNC;   // cnt block + shadows contiguous for 1 memset
    int* cntU = (int*)(ws + off); off += N_FUNC;
    int* cntA = (int*)(ws + off); off += N_API;
    float* shadows = ws + off; off += NSHADOW * 128;
    int* rpC = (int*)(ws + off); off += N_FUNC + 1;
    int* rpU = (int*)(ws + off); off += N_FUNC + 1;
    int* rpA = (int*)(ws + off); off += N_API + 1;
    int* nxC = (int*)(ws + off); off += N_FUNC + 1;
    int* nxU = (int*)(ws + off); off += N_FUNC + 1;
    int* nxA = (int*)(ws + off); off += N_API + 1;
    int* colC = (int*)(ws + off); off += E;
    int* colU = (int*)(ws + off); off += E;
    int* colA = (int*)(ws + off); off += E;
    int* partC = (int*)(ws + off); off += 128;
    int* partU = (int*)(ws + off); off += 128;
    int* partA = (int*)(ws + off); off += 128;

    const int nbF = (N_FUNC + SCAN_CHUNK - 1) / SCAN_CHUNK;  // 98
    const int nbA = (N_API + SCAN_CHUNK - 1) / SCAN_CHUNK;   // 25
    const int fillB = (3 * E + 255) / 256;

    hipMemsetAsync(cntC, 0, (size_t)(2 * N_FUNC + N_API + NSHADOW * 128) * sizeof(float), stream);

    prep_and_count<<<PREP_BLOCKS + fillB, 256, 0, stream>>>(
            w_in_func, w_in_api, Wl_calls, Wr_calls, Wl_uses, Wr_uses,
            Wl_usedby, Wr_usedby, prep,
            ei_calls + E, ei_usedby + E, ei_uses + E, cntC, cntU, cntA, E);

    float* wt_in_func = prep;
    float* wt_in_api  = prep + 8192;
    float* wt_r[NLAYERS], *wt_lc[NLAYERS], *wt_lu[NLAYERS], *wt_luse[NLAYERS], *wt_ruse[NLAYERS];
    for (int l = 0; l < NLAYERS; ++l) {
        wt_r[l]    = prep + 12288 + (l * 5 + 0) * 4096;
        wt_lc[l]   = prep + 12288 + (l * 5 + 1) * 4096;
        wt_lu[l]   = prep + 12288 + (l * 5 + 2) * 4096;
        wt_luse[l] = prep + 12288 + (l * 5 + 3) * 4096;
        wt_ruse[l] = prep + 12288 + (l * 5 + 4) * 4096;
    }

    block_sums_all<<<2 * nbF + nbA, 256, 0, stream>>>(
            cntC, cntU, cntA, partC, partU, partA, N_FUNC, N_API, nbF);
    scan_small_all<<<1, 192, 0, stream>>>(partC, partU, partA, nbF, nbA);
    write_rowptr_all<<<2 * nbF + nbA, 256, 0, stream>>>(
            cntC, cntU, cntA, partC, partU, partA,
            rpC, rpU, rpA, nxC, nxU, nxA, N_FUNC, N_API, nbF, E);
    fill_and_proj<<<fillB + NBF + NBA, 256, 0, stream>>>(
            ei_calls, ei_calls + E, ei_usedby, ei_usedby + E, ei_uses, ei_uses + E,
            nxC, nxU, nxA, colC, colU, colA, E, fillB,
            x_func, wt_in_func, b_in_func, hf0,
            x_api, wt_in_api, b_in_api, ha0);

    u16* hf[2] = { hf0, hf1 };
    u16* ha[2] = { ha0, ha1 };
    for (int l = 0; l < NLAYERS; ++l) {
        int cur = l & 1, nxt = cur ^ 1;
        layer_both<<<NBF + NBA, 256, 0, stream>>>(
                hf[cur], ha[cur], hf[nxt], ha[nxt],
                rpC, colC, rpU, colU, rpA, colA,
                wt_r[l], wt_lc[l], wt_lu[l], wt_ruse[l], wt_luse[l],
                bl_calls + l * 64, bl_usedby + l * 64, bl_uses + l * 64,
                (l == NLAYERS - 1) ? shadows : nullptr);
    }

    classifier_kernel<<<1, 128, 0, stream>>>(shadows, Wc1, bc1, Wc2, bc2, (float*)d_out);
}

// Round 10
// 447.711 us; speedup vs baseline: 1.2577x; 1.2577x over previous
//
#include <hip/hip_runtime.h>

#define N_FUNC 200000
#define N_API  50000
#define H      64
#define NLAYERS 2
#define NBF 3125   // N_FUNC/64 exact
#define NBA 782    // ceil(N_API/64)
#define PREPB 208  // ceil(53248/256) weight-prep blocks
#define NSHADOW 64
#define NBK   391  // buckets per relation: ceil(200000/512) = ceil(50000/128) = 391
#define BCAP  4096 // bucket capacity (mean 1024, +45..96 sigma margin)
#define EPB   4096 // edges per binA block
#define WLOG_F 9   // func dst bucket width 512
#define WLOG_A 7   // api dst bucket width 128

typedef unsigned short u16;

__device__ __forceinline__ void fma4(float4& a, float s, float4 w) {
    a.x = fmaf(s, w.x, a.x); a.y = fmaf(s, w.y, a.y);
    a.z = fmaf(s, w.z, a.z); a.w = fmaf(s, w.w, a.w);
}
__device__ __forceinline__ void add4(float4& a, float4 v) {
    a.x += v.x; a.y += v.y; a.z += v.z; a.w += v.w;
}
__device__ __forceinline__ void scl4(float4& a, float s) {
    a.x *= s; a.y *= s; a.z *= s; a.w *= s;
}
__device__ __forceinline__ float bf2f(u16 u) {
    return __uint_as_float(((unsigned int)u) << 16);
}
__device__ __forceinline__ u16 f2bf(float f) {   // round-to-nearest-even
    unsigned int x = __float_as_uint(f);
    return (u16)((x + 0x7FFFu + ((x >> 16) & 1u)) >> 16);
}
__device__ __forceinline__ float4 b2f4(ushort4 v) {
    return make_float4(bf2f(v.x), bf2f(v.y), bf2f(v.z), bf2f(v.w));
}
__device__ __forceinline__ ushort4 f2b4(float4 o) {
    ushort4 r; r.x = f2bf(o.x); r.y = f2bf(o.y); r.z = f2bf(o.z); r.w = f2bf(o.w);
    return r;
}
__device__ __forceinline__ void addb(float4& a, ushort4 v) {
    a.x += bf2f(v.x); a.y += bf2f(v.y); a.z += bf2f(v.z); a.w += bf2f(v.w);
}

// ==== K1: weight prep (208 blocks) + binA bucket-scatter (rest) ====
__global__ __launch_bounds__(256, 4) void prep_and_binA(
        const float* __restrict__ w_in_func, const float* __restrict__ w_in_api,
        const float* __restrict__ Wl_calls, const float* __restrict__ Wr_calls,
        const float* __restrict__ Wl_uses,  const float* __restrict__ Wr_uses,
        const float* __restrict__ Wl_usedby,const float* __restrict__ Wr_usedby,
        float* __restrict__ out,
        const int* __restrict__ sC, const int* __restrict__ dC,
        const int* __restrict__ sU, const int* __restrict__ dU,
        const int* __restrict__ sA, const int* __restrict__ dA,
        int* __restrict__ bktC, int* __restrict__ bktU, int* __restrict__ bktA,
        int* __restrict__ beC, int* __restrict__ beU, int* __restrict__ beA,
        int E, int nbPerRel)
{
    __shared__ int staged[EPB];
    __shared__ int hist[NBK + 1];
    __shared__ int lcnt[NBK];
    __shared__ int gbase[NBK];
    __shared__ int stemp[256];
    const int b = blockIdx.x, t = threadIdx.x;
    if (b < PREPB) {
        int idx = b * 256 + t;
        if (idx < 8192) {
            int k = idx >> 6, o = idx & 63;
            out[idx] = w_in_func[o * 128 + k];
        } else if (idx < 12288) {
            int r = idx - 8192; int k = r >> 6, o = r & 63;
            out[idx] = w_in_api[o * 64 + k];
        } else if (idx < 12288 + 10 * 4096) {
            int r = idx - 12288;
            int m = r >> 12, w = r & 4095;
            int k = w >> 6, o = w & 63;
            int l = m / 5, which = m - 5 * l;
            const float* A; const float* B = nullptr;
            if (which == 0)      { A = Wr_calls  + l * 4096; B = Wr_usedby + l * 4096; }
            else if (which == 1)   A = Wl_calls  + l * 4096;
            else if (which == 2)   A = Wl_usedby + l * 4096;
            else if (which == 3)   A = Wl_uses   + l * 4096;
            else                   A = Wr_uses   + l * 4096;
            float v = A[o * 64 + k];
            if (B) v += B[o * 64 + k];
            out[idx] = v;
        }
        return;
    }
    int bb = b - PREPB;
    int rel = bb / nbPerRel, lb = bb - rel * nbPerRel;
    const int* srcA; const int* dstA; int* bcnt; int* be; int wlog;
    if (rel == 0)      { srcA = sC; dstA = dC; bcnt = bktC; be = beC; wlog = WLOG_F; }
    else if (rel == 1) { srcA = sU; dstA = dU; bcnt = bktU; be = beU; wlog = WLOG_F; }
    else               { srcA = sA; dstA = dA; bcnt = bktA; be = beA; wlog = WLOG_A; }
    const int mask = (1 << wlog) - 1;
    const int e0 = lb * EPB;
    const int cnt = min(EPB, E - e0);
    for (int i = t; i < NBK; i += 256) { hist[i] = 0; lcnt[i] = 0; }
    __syncthreads();
    // phase 1: bucket histogram
    for (int i = t; i < cnt; i += 256)
        atomicAdd(&hist[dstA[e0 + i] >> wlog], 1);
    __syncthreads();
    // exclusive scan hist -> bases (in place); hist[NBK] = total
    int v0 = (2 * t < NBK) ? hist[2 * t] : 0;
    int v1 = (2 * t + 1 < NBK) ? hist[2 * t + 1] : 0;
    __syncthreads();
    stemp[t] = v0 + v1; __syncthreads();
    for (int s = 1; s < 256; s <<= 1) {
        int x = (t >= s) ? stemp[t - s] : 0;
        __syncthreads(); stemp[t] += x; __syncthreads();
    }
    int base = (t > 0) ? stemp[t - 1] : 0;
    if (2 * t < NBK)     hist[2 * t] = base;
    if (2 * t + 1 < NBK) hist[2 * t + 1] = base + v0;
    if (t == 255) hist[NBK] = stemp[255];
    __syncthreads();
    // phase 2: place packed entries grouped by bucket
    for (int i = t; i < cnt; i += 256) {
        int d = dstA[e0 + i], s = srcA[e0 + i];
        int bin = d >> wlog;
        int loc = atomicAdd(&lcnt[bin], 1);
        staged[hist[bin] + loc] = (s << wlog) | (d & mask);
    }
    __syncthreads();
    // reserve global runs
    for (int i = t; i < NBK; i += 256) {
        int c = hist[i + 1] - hist[i];
        gbase[i] = (c > 0) ? atomicAdd(&bcnt[i], c) : 0;
    }
    __syncthreads();
    // copy runs: wave per bucket stride
    int wv = t >> 6, ln = t & 63;
    for (int bin = wv; bin < NBK; bin += 4) {
        int l0 = hist[bin], c = hist[bin + 1] - l0;
        int gb = gbase[bin];
        for (int k = ln; k < c; k += 64)
            if (gb + k < BCAP)
                be[(size_t)bin * BCAP + gb + k] = staged[l0 + k];
    }
}

// ==== K2: exclusive scan of 3x391 bucket counts ====
__global__ __launch_bounds__(256) void scan_buckets(
        const int* __restrict__ bktC, const int* __restrict__ bktU, const int* __restrict__ bktA,
        int* __restrict__ bbC, int* __restrict__ bbU, int* __restrict__ bbA)
{
    __shared__ int st[256];
    int t = threadIdx.x;
    for (int r = 0; r < 3; ++r) {
        const int* c = (r == 0) ? bktC : (r == 1) ? bktU : bktA;
        int* B = (r == 0) ? bbC : (r == 1) ? bbU : bbA;
        int v0 = (2 * t < NBK) ? min(c[2 * t], BCAP) : 0;
        int v1 = (2 * t + 1 < NBK) ? min(c[2 * t + 1], BCAP) : 0;
        st[t] = v0 + v1; __syncthreads();
        for (int s = 1; s < 256; s <<= 1) {
            int x = (t >= s) ? st[t - s] : 0;
            __syncthreads(); st[t] += x; __syncthreads();
        }
        int base = (t > 0) ? st[t - 1] : 0;
        if (2 * t < NBK)     B[2 * t] = base;
        if (2 * t + 1 < NBK) B[2 * t + 1] = base + v0;
        __syncthreads();
    }
}

// ---- GEMM-accumulate over 64x64 LDS tile (XOR-swizzled) ----
__device__ __forceinline__ void gemm_acc(const float4* X, const float4* __restrict__ wt4,
        int og, int ng, float4 acc[4])
{
    for (int k4 = 0; k4 < 16; ++k4) {
        float4 w0 = wt4[(4 * k4 + 0) * 16 + og];
        float4 w1 = wt4[(4 * k4 + 1) * 16 + og];
        float4 w2 = wt4[(4 * k4 + 2) * 16 + og];
        float4 w3 = wt4[(4 * k4 + 3) * 16 + og];
        #pragma unroll
        for (int j = 0; j < 4; ++j) {
            int n = ng * 4 + j;
            float4 xv = X[n * 16 + (k4 ^ ((n >> 2) & 7))];
            fma4(acc[j], xv.x, w0); fma4(acc[j], xv.y, w1);
            fma4(acc[j], xv.z, w2); fma4(acc[j], xv.w, w3);
        }
    }
}

// ---- proj bodies (16KB LDS); h output bf16 ----
__device__ __forceinline__ void proj_body128(const float* __restrict__ x,
        const float* __restrict__ wt, const float* __restrict__ bias,
        u16* __restrict__ hout, int i0, float4* smem)
{
    const int t = threadIdx.x;
    const int og = t & 15, ng = t >> 4;
    float4 acc[4];
    #pragma unroll
    for (int j = 0; j < 4; ++j) acc[j] = make_float4(0.f, 0.f, 0.f, 0.f);
    const float4* w4 = reinterpret_cast<const float4*>(wt);
    #pragma unroll
    for (int ph = 0; ph < 2; ++ph) {
        if (ph) __syncthreads();
        for (int idx = t; idx < 1024; idx += 256) {
            int n = idx >> 4, k4 = idx & 15;
            smem[n * 16 + (k4 ^ ((n >> 2) & 7))] =
                *reinterpret_cast<const float4*>(x + (size_t)(i0 + n) * 128 + ph * 64 + k4 * 4);
        }
        __syncthreads();
        gemm_acc(smem, w4 + ph * 1024, og, ng, acc);
    }
    float4 b = reinterpret_cast<const float4*>(bias)[og];
    #pragma unroll
    for (int j = 0; j < 4; ++j) {
        int node = i0 + ng * 4 + j;
        float4 o;
        o.x = fmaxf(acc[j].x + b.x, 0.f);
        o.y = fmaxf(acc[j].y + b.y, 0.f);
        o.z = fmaxf(acc[j].z + b.z, 0.f);
        o.w = fmaxf(acc[j].w + b.w, 0.f);
        *reinterpret_cast<ushort4*>(hout + (size_t)node * H + og * 4) = f2b4(o);
    }
}

__device__ __forceinline__ void proj_body64(const float* __restrict__ x,
        const float* __restrict__ wt, const float* __restrict__ bias,
        u16* __restrict__ hout, int i0, int nN, float4* smem)
{
    const int t = threadIdx.x;
    for (int idx = t; idx < 1024; idx += 256) {
        int n = idx >> 4, k4 = idx & 15;
        float4 v = make_float4(0.f, 0.f, 0.f, 0.f);
        if (i0 + n < nN)
            v = *reinterpret_cast<const float4*>(x + (size_t)(i0 + n) * 64 + k4 * 4);
        smem[n * 16 + (k4 ^ ((n >> 2) & 7))] = v;
    }
    __syncthreads();
    const int og = t & 15, ng = t >> 4;
    float4 acc[4];
    #pragma unroll
    for (int j = 0; j < 4; ++j) acc[j] = make_float4(0.f, 0.f, 0.f, 0.f);
    gemm_acc(smem, reinterpret_cast<const float4*>(wt), og, ng, acc);
    float4 b = reinterpret_cast<const float4*>(bias)[og];
    #pragma unroll
    for (int j = 0; j < 4; ++j) {
        int node = i0 + ng * 4 + j;
        if (node < nN) {
            float4 o;
            o.x = fmaxf(acc[j].x + b.x, 0.f);
            o.y = fmaxf(acc[j].y + b.y, 0.f);
            o.z = fmaxf(acc[j].z + b.z, 0.f);
            o.w = fmaxf(acc[j].w + b.w, 0.f);
            *reinterpret_cast<ushort4*>(hout + (size_t)node * H + og * 4) = f2b4(o);
        }
    }
}

// ==== K3: binB (per-bucket local CSR: rp + col) + both projections ====
__global__ __launch_bounds__(256, 4) void binB_and_proj(
        const int* __restrict__ beC, const int* __restrict__ beU, const int* __restrict__ beA,
        const int* __restrict__ bktC, const int* __restrict__ bktU, const int* __restrict__ bktA,
        const int* __restrict__ bbC, const int* __restrict__ bbU, const int* __restrict__ bbA,
        int* __restrict__ rpC, int* __restrict__ rpU, int* __restrict__ rpA,
        int* __restrict__ colC, int* __restrict__ colU, int* __restrict__ colA,
        const float* __restrict__ xf, const float* __restrict__ wtf,
        const float* __restrict__ bf, u16* __restrict__ hf,
        const float* __restrict__ xa, const float* __restrict__ wta,
        const float* __restrict__ ba_, u16* __restrict__ ha)
{
    __shared__ __align__(16) int shraw[BCAP + 513 + 512];   // ~20.1 KB
    const int b = blockIdx.x, t = threadIdx.x;
    if (b < 3 * NBK) {
        int rel = b / NBK, bkt = b - rel * NBK;
        const int* be; const int* bc; const int* bbs; int* rp; int* col; int wlog, n;
        if (rel == 0)      { be = beC; bc = bktC; bbs = bbC; rp = rpC; col = colC; wlog = WLOG_F; n = N_FUNC; }
        else if (rel == 1) { be = beU; bc = bktU; bbs = bbU; rp = rpU; col = colU; wlog = WLOG_F; n = N_FUNC; }
        else               { be = beA; bc = bktA; bbs = bbA; rp = rpA; col = colA; wlog = WLOG_A; n = N_API; }
        const int width = 1 << wlog, mask = width - 1;
        const int nodeBase = bkt << wlog;
        const int nN = min(width, n - nodeBase);
        const int cnt = min(bc[bkt], BCAP);
        const int gb = bbs[bkt];
        int* colS = shraw;
        int* lrp  = shraw + BCAP;        // [513]
        int* nxL  = shraw + BCAP + 513;  // [512]
        for (int i = t; i <= 512; i += 256) { lrp[i] = 0; if (i < 512) nxL[i] = 0; }
        __syncthreads();
        const int* bePtr = be + (size_t)bkt * BCAP;
        for (int i = t; i < cnt; i += 256)
            atomicAdd(&lrp[bePtr[i] & mask], 1);
        __syncthreads();
        // exclusive scan lrp[0..512) using colS as temp
        int v0 = lrp[2 * t], v1 = lrp[2 * t + 1];
        __syncthreads();
        int* st = colS;
        st[t] = v0 + v1; __syncthreads();
        for (int s = 1; s < 256; s <<= 1) {
            int x = (t >= s) ? st[t - s] : 0;
            __syncthreads(); st[t] += x; __syncthreads();
        }
        int base0 = (t > 0) ? st[t - 1] : 0;
        lrp[2 * t] = base0; lrp[2 * t + 1] = base0 + v0;
        if (t == 255) lrp[512] = st[255];
        __syncthreads();
        // write rowptr segment (coalesced)
        for (int i = t; i < nN; i += 256) rp[nodeBase + i] = gb + lrp[i];
        if (nodeBase + nN == n && t == 0) rp[n] = gb + lrp[nN];
        __syncthreads();   // done with colS-as-temp
        // scatter col entries into LDS, flush coalesced
        for (int i = t; i < cnt; i += 256) {
            int en = bePtr[i]; int dl = en & mask;
            int pos = lrp[dl] + atomicAdd(&nxL[dl], 1);
            colS[pos] = en >> wlog;
        }
        __syncthreads();
        for (int i = t; i < cnt; i += 256) col[gb + i] = colS[i];
    } else {
        int b2 = b - 3 * NBK;
        float4* smem = reinterpret_cast<float4*>(shraw);
        if (b2 < NBF) proj_body128(xf, wtf, bf, hf, b2 * 64, smem);
        else          proj_body64(xa, wta, ba_, ha, (b2 - NBF) * 64, N_API, smem);
    }
}

// ---- 8-deep interleaved CSR gather on bf16 rows ----
__device__ __forceinline__ void gather8(const u16* __restrict__ src,
        const int* __restrict__ col, int j[4], const int e[4], int L, float4 a[4])
{
    while (j[0] < e[0] || j[1] < e[1] || j[2] < e[2] || j[3] < e[3]) {
        ushort4 v[8]; bool act[8];
        #pragma unroll
        for (int p = 0; p < 4; ++p) {
            int jj = j[p];
            act[2 * p]     = jj < e[p];
            act[2 * p + 1] = jj + 1 < e[p];
            if (act[2 * p]) {
                int s = col[jj];
                v[2 * p] = *reinterpret_cast<const ushort4*>(src + (size_t)s * H + L * 4);
            }
            if (act[2 * p + 1]) {
                int s = col[jj + 1];
                v[2 * p + 1] = *reinterpret_cast<const ushort4*>(src + (size_t)s * H + L * 4);
            }
            j[p] = jj + 2;
        }
        #pragma unroll
        for (int q = 0; q < 8; ++q) if (act[q]) addb(a[q >> 1], v[q]);
    }
}

// ---- fused layer: bf16 h in/out, fp32 compute; optional fused mean-pool ----
__global__ __launch_bounds__(256, 4) void layer_both(
        const u16* __restrict__ hf_old, const u16* __restrict__ ha_old,
        u16* __restrict__ hf_new, u16* __restrict__ ha_new,
        const int* __restrict__ rpC, const int* __restrict__ colC,
        const int* __restrict__ rpU, const int* __restrict__ colU,
        const int* __restrict__ rpA, const int* __restrict__ colA,
        const float* __restrict__ wtr, const float* __restrict__ wtlc,
        const float* __restrict__ wtlu,
        const float* __restrict__ wtruse, const float* __restrict__ wtluse,
        const float* __restrict__ bias_c, const float* __restrict__ bias_u,
        const float* __restrict__ bias_a,
        float* __restrict__ psh)
{
    __shared__ __align__(16) float4 X[64 * 16];
    const int b = blockIdx.x;
    const int t = threadIdx.x;
    const int L = t & 15, g = t >> 4;
    const int og = t & 15, ng = t >> 4;
    const float4 z4 = make_float4(0.f, 0.f, 0.f, 0.f);

    float4 acc[4];
    #pragma unroll
    for (int j = 0; j < 4; ++j) acc[j] = z4;
    float4 o4[4];
    #pragma unroll
    for (int j = 0; j < 4; ++j) o4[j] = z4;

    if (b < NBF) {
        const int i0 = b * 64;
        {
            int j1[4], e1[4], d1[4]; float4 a1[4];
            #pragma unroll
            for (int p = 0; p < 4; ++p) {
                int node = i0 + p * 16 + g;
                j1[p] = rpC[node]; e1[p] = rpC[node + 1]; d1[p] = e1[p] - j1[p];
                a1[p] = z4;
            }
            gather8(hf_old, colC, j1, e1, L, a1);
            #pragma unroll
            for (int p = 0; p < 4; ++p) {
                int n = p * 16 + g;
                scl4(a1[p], 1.0f / (float)max(d1[p], 1));
                X[n * 16 + (L ^ ((n >> 2) & 7))] = a1[p];
            }
        }
        __syncthreads();
        gemm_acc(X, reinterpret_cast<const float4*>(wtlc), og, ng, acc);
        __syncthreads();
        {
            int j2[4], e2[4], d2[4]; float4 a2[4];
            #pragma unroll
            for (int p = 0; p < 4; ++p) {
                int node = i0 + p * 16 + g;
                j2[p] = rpU[node]; e2[p] = rpU[node + 1]; d2[p] = e2[p] - j2[p];
                a2[p] = z4;
            }
            gather8(ha_old, colU, j2, e2, L, a2);
            #pragma unroll
            for (int p = 0; p < 4; ++p) {
                int n = p * 16 + g;
                scl4(a2[p], 1.0f / (float)max(d2[p], 1));
                X[n * 16 + (L ^ ((n >> 2) & 7))] = a2[p];
            }
        }
        __syncthreads();
        ushort4 ow[4];
        #pragma unroll
        for (int r = 0; r < 4; ++r) {
            int idx = t + r * 256;
            int n = idx >> 4, k4 = idx & 15;
            ow[r] = *reinterpret_cast<const ushort4*>(hf_old + (size_t)(i0 + n) * H + k4 * 4);
        }
        gemm_acc(X, reinterpret_cast<const float4*>(wtlu), og, ng, acc);
        __syncthreads();
        #pragma unroll
        for (int r = 0; r < 4; ++r) {
            int idx = t + r * 256;
            int n = idx >> 4, k4 = idx & 15;
            X[n * 16 + (k4 ^ ((n >> 2) & 7))] = b2f4(ow[r]);
        }
        __syncthreads();
        gemm_acc(X, reinterpret_cast<const float4*>(wtr), og, ng, acc);
        float4 ba = reinterpret_cast<const float4*>(bias_c)[og];
        float4 bb = reinterpret_cast<const float4*>(bias_u)[og];
        float4 bv = make_float4(ba.x + bb.x, ba.y + bb.y, ba.z + bb.z, ba.w + bb.w);
        #pragma unroll
        for (int j = 0; j < 4; ++j) {
            int node = i0 + ng * 4 + j;
            float4 o;
            o.x = fmaxf(acc[j].x + bv.x, 0.f);
            o.y = fmaxf(acc[j].y + bv.y, 0.f);
            o.z = fmaxf(acc[j].z + bv.z, 0.f);
            o.w = fmaxf(acc[j].w + bv.w, 0.f);
            o4[j] = o;
            *reinterpret_cast<ushort4*>(hf_new + (size_t)node * H + og * 4) = f2b4(o);
        }
        if (psh) {
            float4 s = z4;
            #pragma unroll
            for (int j = 0; j < 4; ++j) add4(s, o4[j]);
            __syncthreads();
            X[ng * 16 + og] = s;
            __syncthreads();
            if (ng == 0) {
                float4 tot = z4;
                #pragma unroll
                for (int q = 0; q < 16; ++q) add4(tot, X[q * 16 + og]);
                float* dst = psh + (size_t)(b & (NSHADOW - 1)) * 128 + og * 4;
                atomicAdd(dst + 0, tot.x); atomicAdd(dst + 1, tot.y);
                atomicAdd(dst + 2, tot.z); atomicAdd(dst + 3, tot.w);
            }
        }
    } else {
        const int i0 = (b - NBF) * 64;
        {
            int j1[4], e1[4], d1[4]; float4 a1[4];
            #pragma unroll
            for (int p = 0; p < 4; ++p) {
                int node = i0 + p * 16 + g;
                if (node < N_API) { j1[p] = rpA[node]; e1[p] = rpA[node + 1]; }
                else { j1[p] = 0; e1[p] = 0; }
                d1[p] = e1[p] - j1[p];
                a1[p] = z4;
            }
            gather8(hf_old, colA, j1, e1, L, a1);
            #pragma unroll
            for (int p = 0; p < 4; ++p) {
                int n = p * 16 + g;
                scl4(a1[p], 1.0f / (float)max(d1[p], 1));
                X[n * 16 + (L ^ ((n >> 2) & 7))] = a1[p];
            }
        }
        __syncthreads();
        ushort4 ow[4];
        #pragma unroll
        for (int r = 0; r < 4; ++r) {
            int idx = t + r * 256;
            int n = idx >> 4, k4 = idx & 15;
            int node = i0 + n;
            ow[r] = make_ushort4(0, 0, 0, 0);
            if (node < N_API)
                ow[r] = *reinterpret_cast<const ushort4*>(ha_old + (size_t)node * H + k4 * 4);
        }
        gemm_acc(X, reinterpret_cast<const float4*>(wtluse), og, ng, acc);
        __syncthreads();
        #pragma unroll
        for (int r = 0; r < 4; ++r) {
            int idx = t + r * 256;
            int n = idx >> 4, k4 = idx & 15;
            X[n * 16 + (k4 ^ ((n >> 2) & 7))] = b2f4(ow[r]);
        }
        __syncthreads();
        gemm_acc(X, reinterpret_cast<const float4*>(wtruse), og, ng, acc);
        float4 bv = reinterpret_cast<const float4*>(bias_a)[og];
        #pragma unroll
        for (int j = 0; j < 4; ++j) {
            int node = i0 + ng * 4 + j;
            if (node < N_API) {
                float4 o;
                o.x = fmaxf(acc[j].x + bv.x, 0.f);
                o.y = fmaxf(acc[j].y + bv.y, 0.f);
                o.z = fmaxf(acc[j].z + bv.z, 0.f);
                o.w = fmaxf(acc[j].w + bv.w, 0.f);
                o4[j] = o;
                *reinterpret_cast<ushort4*>(ha_new + (size_t)node * H + og * 4) = f2b4(o);
            }
        }
        if (psh) {
            float4 s = z4;
            #pragma unroll
            for (int j = 0; j < 4; ++j) add4(s, o4[j]);
            __syncthreads();
            X[ng * 16 + og] = s;
            __syncthreads();
            if (ng == 0) {
                float4 tot = z4;
                #pragma unroll
                for (int q = 0; q < 16; ++q) add4(tot, X[q * 16 + og]);
                float* dst = psh + (size_t)(b & (NSHADOW - 1)) * 128 + 64 + og * 4;
                atomicAdd(dst + 0, tot.x); atomicAdd(dst + 1, tot.y);
                atomicAdd(dst + 2, tot.z); atomicAdd(dst + 3, tot.w);
            }
        }
    }
}

__global__ __launch_bounds__(128) void classifier_kernel(const float* __restrict__ shadows,
        const float* __restrict__ Wc1, const float* __restrict__ bc1,
        const float* __restrict__ Wc2, const float* __restrict__ bc2,
        float* __restrict__ out)
{
    __shared__ float ps[128];
    __shared__ float z1[64];
    int t = threadIdx.x;
    float s = 0.f;
    for (int q = 0; q < NSHADOW; ++q) s += shadows[q * 128 + t];
    ps[t] = s * (t < 64 ? (1.0f / N_FUNC) : (1.0f / N_API));
    __syncthreads();
    if (t < 64) {
        float a = bc1[t];
        for (int k = 0; k < 128; ++k) a = fmaf(ps[k], Wc1[t * 128 + k], a);
        z1[t] = fmaxf(a, 0.f);
    }
    __syncthreads();
    if (t < 2) {
        float a = bc2[t];
        for (int j = 0; j < 64; ++j) a = fmaf(z1[j], Wc2[t * 64 + j], a);
        out[t] = a;
    }
}

extern "C" void kernel_launch(void* const* d_in, const int* in_sizes, int n_in,
                              void* d_out, int out_size, void* d_ws, size_t ws_size,
                              hipStream_t stream)
{
    const float* x_func    = (const float*)d_in[0];
    const float* x_api     = (const float*)d_in[1];
    const float* w_in_func = (const float*)d_in[2];
    const float* b_in_func = (const float*)d_in[3];
    const float* w_in_api  = (const float*)d_in[4];
    const float* b_in_api  = (const float*)d_in[5];
    const float* Wl_calls  = (const float*)d_in[6];
    const float* bl_calls  = (const float*)d_in[7];
    const float* Wr_calls  = (const float*)d_in[8];
    const float* Wl_uses   = (const float*)d_in[9];
    const float* bl_uses   = (const float*)d_in[10];
    const float* Wr_uses   = (const float*)d_in[11];
    const float* Wl_usedby = (const float*)d_in[12];
    const float* bl_usedby = (const float*)d_in[13];
    const float* Wr_usedby = (const float*)d_in[14];
    const float* Wc1       = (const float*)d_in[15];
    const float* bc1       = (const float*)d_in[16];
    const float* Wc2       = (const float*)d_in[17];
    const float* bc2       = (const float*)d_in[18];
    const int*   ei_calls  = (const int*)d_in[19];
    const int*   ei_uses   = (const int*)d_in[20];
    const int*   ei_usedby = (const int*)d_in[21];
    const int E = in_sizes[19] / 2;

    float* ws = (float*)d_ws;
    size_t off = 0;
    u16* hf0 = (u16*)(ws + off); off += (size_t)N_FUNC * 32;
    u16* hf1 = (u16*)(ws + off); off += (size_t)N_FUNC * 32;
    u16* ha0 = (u16*)(ws + off); off += (size_t)N_API * 32;
    u16* ha1 = (u16*)(ws + off); off += (size_t)N_API * 32;
    float* prep = ws + off; off += 12288 + 10 * 4096;
    // memset block: bucket counts (3*NBK) + shadows
    int* bktC = (int*)(ws + off); off += NBK;
    int* bktU = (int*)(ws + off); off += NBK;
    int* bktA = (int*)(ws + off); off += NBK;
    float* shadows = ws + off; off += NSHADOW * 128;
    int* bbC = (int*)(ws + off); off += NBK;
    int* bbU = (int*)(ws + off); off += NBK;
    int* bbA = (int*)(ws + off); off += NBK;
    int* rpC = (int*)(ws + off); off += N_FUNC + 1;
    int* rpU = (int*)(ws + off); off += N_FUNC + 1;
    int* rpA = (int*)(ws + off); off += N_API + 1;
    int* colC = (int*)(ws + off); off += E;
    int* colU = (int*)(ws + off); off += E;
    int* colA = (int*)(ws + off); off += E;
    int* beC = (int*)(ws + off); off += (size_t)NBK * BCAP;
    int* beU = (int*)(ws + off); off += (size_t)NBK * BCAP;
    int* beA = (int*)(ws + off); off += (size_t)NBK * BCAP;

    const int nbPerRel = (E + EPB - 1) / EPB;   // 98

    hipMemsetAsync(bktC, 0, (size_t)(3 * NBK + NSHADOW * 128) * sizeof(float), stream);

    prep_and_binA<<<PREPB + 3 * nbPerRel, 256, 0, stream>>>(
            w_in_func, w_in_api, Wl_calls, Wr_calls, Wl_uses, Wr_uses,
            Wl_usedby, Wr_usedby, prep,
            ei_calls, ei_calls + E, ei_usedby, ei_usedby + E, ei_uses, ei_uses + E,
            bktC, bktU, bktA, beC, beU, beA, E, nbPerRel);

    scan_buckets<<<1, 256, 0, stream>>>(bktC, bktU, bktA, bbC, bbU, bbA);

    float* wt_in_func = prep;
    float* wt_in_api  = prep + 8192;
    float* wt_r[NLAYERS], *wt_lc[NLAYERS], *wt_lu[NLAYERS], *wt_luse[NLAYERS], *wt_ruse[NLAYERS];
    for (int l = 0; l < NLAYERS; ++l) {
        wt_r[l]    = prep + 12288 + (l * 5 + 0) * 4096;
        wt_lc[l]   = prep + 12288 + (l * 5 + 1) * 4096;
        wt_lu[l]   = prep + 12288 + (l * 5 + 2) * 4096;
        wt_luse[l] = prep + 12288 + (l * 5 + 3) * 4096;
        wt_ruse[l] = prep + 12288 + (l * 5 + 4) * 4096;
    }

    binB_and_proj<<<3 * NBK + NBF + NBA, 256, 0, stream>>>(
            beC, beU, beA, bktC, bktU, bktA, bbC, bbU, bbA,
            rpC, rpU, rpA, colC, colU, colA,
            x_func, wt_in_func, b_in_func, hf0,
            x_api, wt_in_api, b_in_api, ha0);

    u16* hf[2] = { hf0, hf1 };
    u16* ha[2] = { ha0, ha1 };
    for (int l = 0; l < NLAYERS; ++l) {
        int cur = l & 1, nxt = cur ^ 1;
        layer_both<<<NBF + NBA, 256, 0, stream>>>(
                hf[cur], ha[cur], hf[nxt], ha[nxt],
                rpC, colC, rpU, colU, rpA, colA,
                wt_r[l], wt_lc[l], wt_lu[l], wt_ruse[l], wt_luse[l],
                bl_calls + l * 64, bl_usedby + l * 64, bl_uses + l * 64,
                (l == NLAYERS - 1) ? shadows : nullptr);
    }

    classifier_kernel<<<1, 128, 0, stream>>>(shadows, Wc1, bc1, Wc2, bc2, (float*)d_out);
}

// Round 11
// 415.202 us; speedup vs baseline: 1.3562x; 1.0783x over previous
//
#include <hip/hip_runtime.h>

#define N_FUNC 200000
#define N_API  50000
#define H      64
#define NLAYERS 2
#define NBF 3125   // N_FUNC/64 exact
#define NBA 782    // ceil(N_API/64)
#define PREPB 208  // ceil(53248/256) weight-prep blocks
#define NSHADOW 64
#define NBK   391  // buckets per relation
#define BCAP  4096
#define EPB   4096
#define WLOG_F 9
#define WLOG_A 7

typedef unsigned short u16;

__device__ __forceinline__ void fma4(float4& a, float s, float4 w) {
    a.x = fmaf(s, w.x, a.x); a.y = fmaf(s, w.y, a.y);
    a.z = fmaf(s, w.z, a.z); a.w = fmaf(s, w.w, a.w);
}
__device__ __forceinline__ void add4(float4& a, float4 v) {
    a.x += v.x; a.y += v.y; a.z += v.z; a.w += v.w;
}
__device__ __forceinline__ void scl4(float4& a, float s) {
    a.x *= s; a.y *= s; a.z *= s; a.w *= s;
}
__device__ __forceinline__ float bf2f(u16 u) {
    return __uint_as_float(((unsigned int)u) << 16);
}
__device__ __forceinline__ u16 f2bf(float f) {
    unsigned int x = __float_as_uint(f);
    return (u16)((x + 0x7FFFu + ((x >> 16) & 1u)) >> 16);
}
__device__ __forceinline__ float4 b2f4(ushort4 v) {
    return make_float4(bf2f(v.x), bf2f(v.y), bf2f(v.z), bf2f(v.w));
}
__device__ __forceinline__ ushort4 f2b4(float4 o) {
    ushort4 r; r.x = f2bf(o.x); r.y = f2bf(o.y); r.z = f2bf(o.z); r.w = f2bf(o.w);
    return r;
}
__device__ __forceinline__ void addb(float4& a, ushort4 v) {
    a.x += bf2f(v.x); a.y += bf2f(v.y); a.z += bf2f(v.z); a.w += bf2f(v.w);
}

// ==== K1: weight prep + binA bucket-scatter ====
__global__ __launch_bounds__(256, 6) void prep_and_binA(
        const float* __restrict__ w_in_func, const float* __restrict__ w_in_api,
        const float* __restrict__ Wl_calls, const float* __restrict__ Wr_calls,
        const float* __restrict__ Wl_uses,  const float* __restrict__ Wr_uses,
        const float* __restrict__ Wl_usedby,const float* __restrict__ Wr_usedby,
        float* __restrict__ out,
        const int* __restrict__ sC, const int* __restrict__ dC,
        const int* __restrict__ sU, const int* __restrict__ dU,
        const int* __restrict__ sA, const int* __restrict__ dA,
        int* __restrict__ bktC, int* __restrict__ bktU, int* __restrict__ bktA,
        int* __restrict__ beC, int* __restrict__ beU, int* __restrict__ beA,
        int E, int nbPerRel)
{
    __shared__ int staged[EPB];
    __shared__ int hist[NBK + 1];
    __shared__ int lcnt[NBK];
    __shared__ int gbase[NBK];
    __shared__ int stemp[256];
    const int b = blockIdx.x, t = threadIdx.x;
    if (b < PREPB) {
        int idx = b * 256 + t;
        if (idx < 8192) {
            int k = idx >> 6, o = idx & 63;
            out[idx] = w_in_func[o * 128 + k];
        } else if (idx < 12288) {
            int r = idx - 8192; int k = r >> 6, o = r & 63;
            out[idx] = w_in_api[o * 64 + k];
        } else if (idx < 12288 + 10 * 4096) {
            int r = idx - 12288;
            int m = r >> 12, w = r & 4095;
            int k = w >> 6, o = w & 63;
            int l = m / 5, which = m - 5 * l;
            const float* A; const float* B = nullptr;
            if (which == 0)      { A = Wr_calls  + l * 4096; B = Wr_usedby + l * 4096; }
            else if (which == 1)   A = Wl_calls  + l * 4096;
            else if (which == 2)   A = Wl_usedby + l * 4096;
            else if (which == 3)   A = Wl_uses   + l * 4096;
            else                   A = Wr_uses   + l * 4096;
            float v = A[o * 64 + k];
            if (B) v += B[o * 64 + k];
            out[idx] = v;
        }
        return;
    }
    int bb = b - PREPB;
    int rel = bb / nbPerRel, lb = bb - rel * nbPerRel;
    const int* srcA; const int* dstA; int* bcnt; int* be; int wlog;
    if (rel == 0)      { srcA = sC; dstA = dC; bcnt = bktC; be = beC; wlog = WLOG_F; }
    else if (rel == 1) { srcA = sU; dstA = dU; bcnt = bktU; be = beU; wlog = WLOG_F; }
    else               { srcA = sA; dstA = dA; bcnt = bktA; be = beA; wlog = WLOG_A; }
    const int mask = (1 << wlog) - 1;
    const int e0 = lb * EPB;
    const int cnt = min(EPB, E - e0);
    for (int i = t; i < NBK; i += 256) { hist[i] = 0; lcnt[i] = 0; }
    __syncthreads();
    for (int i = t; i < cnt; i += 256)
        atomicAdd(&hist[dstA[e0 + i] >> wlog], 1);
    __syncthreads();
    int v0 = (2 * t < NBK) ? hist[2 * t] : 0;
    int v1 = (2 * t + 1 < NBK) ? hist[2 * t + 1] : 0;
    __syncthreads();
    stemp[t] = v0 + v1; __syncthreads();
    for (int s = 1; s < 256; s <<= 1) {
        int x = (t >= s) ? stemp[t - s] : 0;
        __syncthreads(); stemp[t] += x; __syncthreads();
    }
    int base = (t > 0) ? stemp[t - 1] : 0;
    if (2 * t < NBK)     hist[2 * t] = base;
    if (2 * t + 1 < NBK) hist[2 * t + 1] = base + v0;
    if (t == 255) hist[NBK] = stemp[255];
    __syncthreads();
    for (int i = t; i < cnt; i += 256) {
        int d = dstA[e0 + i], s = srcA[e0 + i];
        int bin = d >> wlog;
        int loc = atomicAdd(&lcnt[bin], 1);
        staged[hist[bin] + loc] = (s << wlog) | (d & mask);
    }
    __syncthreads();
    for (int i = t; i < NBK; i += 256) {
        int c = hist[i + 1] - hist[i];
        gbase[i] = (c > 0) ? atomicAdd(&bcnt[i], c) : 0;
    }
    __syncthreads();
    int wv = t >> 6, ln = t & 63;
    for (int bin = wv; bin < NBK; bin += 4) {
        int l0 = hist[bin], c = hist[bin + 1] - l0;
        int gb = gbase[bin];
        for (int k = ln; k < c; k += 64)
            if (gb + k < BCAP)
                be[(size_t)bin * BCAP + gb + k] = staged[l0 + k];
    }
}

// ==== K2: exclusive scan of 3x391 bucket counts ====
__global__ __launch_bounds__(256) void scan_buckets(
        const int* __restrict__ bktC, const int* __restrict__ bktU, const int* __restrict__ bktA,
        int* __restrict__ bbC, int* __restrict__ bbU, int* __restrict__ bbA)
{
    __shared__ int st[256];
    int t = threadIdx.x;
    for (int r = 0; r < 3; ++r) {
        const int* c = (r == 0) ? bktC : (r == 1) ? bktU : bktA;
        int* B = (r == 0) ? bbC : (r == 1) ? bbU : bbA;
        int v0 = (2 * t < NBK) ? min(c[2 * t], BCAP) : 0;
        int v1 = (2 * t + 1 < NBK) ? min(c[2 * t + 1], BCAP) : 0;
        st[t] = v0 + v1; __syncthreads();
        for (int s = 1; s < 256; s <<= 1) {
            int x = (t >= s) ? st[t - s] : 0;
            __syncthreads(); st[t] += x; __syncthreads();
        }
        int base = (t > 0) ? st[t - 1] : 0;
        if (2 * t < NBK)     B[2 * t] = base;
        if (2 * t + 1 < NBK) B[2 * t + 1] = base + v0;
        __syncthreads();
    }
}

// ---- GEMM-accumulate over 64x64 LDS tile (XOR-swizzled) ----
__device__ __forceinline__ void gemm_acc(const float4* X, const float4* __restrict__ wt4,
        int og, int ng, float4 acc[4])
{
    for (int k4 = 0; k4 < 16; ++k4) {
        float4 w0 = wt4[(4 * k4 + 0) * 16 + og];
        float4 w1 = wt4[(4 * k4 + 1) * 16 + og];
        float4 w2 = wt4[(4 * k4 + 2) * 16 + og];
        float4 w3 = wt4[(4 * k4 + 3) * 16 + og];
        #pragma unroll
        for (int j = 0; j < 4; ++j) {
            int n = ng * 4 + j;
            float4 xv = X[n * 16 + (k4 ^ ((n >> 2) & 7))];
            fma4(acc[j], xv.x, w0); fma4(acc[j], xv.y, w1);
            fma4(acc[j], xv.z, w2); fma4(acc[j], xv.w, w3);
        }
    }
}

// ---- proj bodies (16KB LDS); h output bf16 ----
__device__ __forceinline__ void proj_body128(const float* __restrict__ x,
        const float* __restrict__ wt, const float* __restrict__ bias,
        u16* __restrict__ hout, int i0, float4* smem)
{
    const int t = threadIdx.x;
    const int og = t & 15, ng = t >> 4;
    float4 acc[4];
    #pragma unroll
    for (int j = 0; j < 4; ++j) acc[j] = make_float4(0.f, 0.f, 0.f, 0.f);
    const float4* w4 = reinterpret_cast<const float4*>(wt);
    #pragma unroll
    for (int ph = 0; ph < 2; ++ph) {
        if (ph) __syncthreads();
        for (int idx = t; idx < 1024; idx += 256) {
            int n = idx >> 4, k4 = idx & 15;
            smem[n * 16 + (k4 ^ ((n >> 2) & 7))] =
                *reinterpret_cast<const float4*>(x + (size_t)(i0 + n) * 128 + ph * 64 + k4 * 4);
        }
        __syncthreads();
        gemm_acc(smem, w4 + ph * 1024, og, ng, acc);
    }
    float4 b = reinterpret_cast<const float4*>(bias)[og];
    #pragma unroll
    for (int j = 0; j < 4; ++j) {
        int node = i0 + ng * 4 + j;
        float4 o;
        o.x = fmaxf(acc[j].x + b.x, 0.f);
        o.y = fmaxf(acc[j].y + b.y, 0.f);
        o.z = fmaxf(acc[j].z + b.z, 0.f);
        o.w = fmaxf(acc[j].w + b.w, 0.f);
        *reinterpret_cast<ushort4*>(hout + (size_t)node * H + og * 4) = f2b4(o);
    }
}

__device__ __forceinline__ void proj_body64(const float* __restrict__ x,
        const float* __restrict__ wt, const float* __restrict__ bias,
        u16* __restrict__ hout, int i0, int nN, float4* smem)
{
    const int t = threadIdx.x;
    for (int idx = t; idx < 1024; idx += 256) {
        int n = idx >> 4, k4 = idx & 15;
        float4 v = make_float4(0.f, 0.f, 0.f, 0.f);
        if (i0 + n < nN)
            v = *reinterpret_cast<const float4*>(x + (size_t)(i0 + n) * 64 + k4 * 4);
        smem[n * 16 + (k4 ^ ((n >> 2) & 7))] = v;
    }
    __syncthreads();
    const int og = t & 15, ng = t >> 4;
    float4 acc[4];
    #pragma unroll
    for (int j = 0; j < 4; ++j) acc[j] = make_float4(0.f, 0.f, 0.f, 0.f);
    gemm_acc(smem, reinterpret_cast<const float4*>(wt), og, ng, acc);
    float4 b = reinterpret_cast<const float4*>(bias)[og];
    #pragma unroll
    for (int j = 0; j < 4; ++j) {
        int node = i0 + ng * 4 + j;
        if (node < nN) {
            float4 o;
            o.x = fmaxf(acc[j].x + b.x, 0.f);
            o.y = fmaxf(acc[j].y + b.y, 0.f);
            o.z = fmaxf(acc[j].z + b.z, 0.f);
            o.w = fmaxf(acc[j].w + b.w, 0.f);
            *reinterpret_cast<ushort4*>(hout + (size_t)node * H + og * 4) = f2b4(o);
        }
    }
}

// ==== K3: binB (per-bucket local CSR) + both projections ====
__global__ __launch_bounds__(256, 6) void binB_and_proj(
        const int* __restrict__ beC, const int* __restrict__ beU, const int* __restrict__ beA,
        const int* __restrict__ bktC, const int* __restrict__ bktU, const int* __restrict__ bktA,
        const int* __restrict__ bbC, const int* __restrict__ bbU, const int* __restrict__ bbA,
        int* __restrict__ rpC, int* __restrict__ rpU, int* __restrict__ rpA,
        int* __restrict__ colC, int* __restrict__ colU, int* __restrict__ colA,
        const float* __restrict__ xf, const float* __restrict__ wtf,
        const float* __restrict__ bf, u16* __restrict__ hf,
        const float* __restrict__ xa, const float* __restrict__ wta,
        const float* __restrict__ ba_, u16* __restrict__ ha)
{
    __shared__ __align__(16) int shraw[BCAP + 513 + 512];   // ~20.1 KB
    const int b = blockIdx.x, t = threadIdx.x;
    if (b < 3 * NBK) {
        int rel = b / NBK, bkt = b - rel * NBK;
        const int* be; const int* bc; const int* bbs; int* rp; int* col; int wlog, n;
        if (rel == 0)      { be = beC; bc = bktC; bbs = bbC; rp = rpC; col = colC; wlog = WLOG_F; n = N_FUNC; }
        else if (rel == 1) { be = beU; bc = bktU; bbs = bbU; rp = rpU; col = colU; wlog = WLOG_F; n = N_FUNC; }
        else               { be = beA; bc = bktA; bbs = bbA; rp = rpA; col = colA; wlog = WLOG_A; n = N_API; }
        const int width = 1 << wlog, mask = width - 1;
        const int nodeBase = bkt << wlog;
        const int nN = min(width, n - nodeBase);
        const int cnt = min(bc[bkt], BCAP);
        const int gb = bbs[bkt];
        int* colS = shraw;
        int* lrp  = shraw + BCAP;
        int* nxL  = shraw + BCAP + 513;
        for (int i = t; i <= 512; i += 256) { lrp[i] = 0; if (i < 512) nxL[i] = 0; }
        __syncthreads();
        const int* bePtr = be + (size_t)bkt * BCAP;
        for (int i = t; i < cnt; i += 256)
            atomicAdd(&lrp[bePtr[i] & mask], 1);
        __syncthreads();
        int v0 = lrp[2 * t], v1 = lrp[2 * t + 1];
        __syncthreads();
        int* st = colS;
        st[t] = v0 + v1; __syncthreads();
        for (int s = 1; s < 256; s <<= 1) {
            int x = (t >= s) ? st[t - s] : 0;
            __syncthreads(); st[t] += x; __syncthreads();
        }
        int base0 = (t > 0) ? st[t - 1] : 0;
        lrp[2 * t] = base0; lrp[2 * t + 1] = base0 + v0;
        if (t == 255) lrp[512] = st[255];
        __syncthreads();
        for (int i = t; i < nN; i += 256) rp[nodeBase + i] = gb + lrp[i];
        if (nodeBase + nN == n && t == 0) rp[n] = gb + lrp[nN];
        __syncthreads();
        for (int i = t; i < cnt; i += 256) {
            int en = bePtr[i]; int dl = en & mask;
            int pos = lrp[dl] + atomicAdd(&nxL[dl], 1);
            colS[pos] = en >> wlog;
        }
        __syncthreads();
        for (int i = t; i < cnt; i += 256) col[gb + i] = colS[i];
    } else {
        int b2 = b - 3 * NBK;
        float4* smem = reinterpret_cast<float4*>(shraw);
        if (b2 < NBF) proj_body128(xf, wtf, bf, hf, b2 * 64, smem);
        else          proj_body64(xa, wta, ba_, ha, (b2 - NBF) * 64, N_API, smem);
    }
}

// ---- 8-deep interleaved CSR gather on bf16 rows ----
__device__ __forceinline__ void gather8(const u16* __restrict__ src,
        const int* __restrict__ col, int j[4], const int e[4], int L, float4 a[4])
{
    while (j[0] < e[0] || j[1] < e[1] || j[2] < e[2] || j[3] < e[3]) {
        ushort4 v[8]; bool act[8];
        #pragma unroll
        for (int p = 0; p < 4; ++p) {
            int jj = j[p];
            act[2 * p]     = jj < e[p];
            act[2 * p + 1] = jj + 1 < e[p];
            if (act[2 * p]) {
                int s = col[jj];
                v[2 * p] = *reinterpret_cast<const ushort4*>(src + (size_t)s * H + L * 4);
            }
            if (act[2 * p + 1]) {
                int s = col[jj + 1];
                v[2 * p + 1] = *reinterpret_cast<const ushort4*>(src + (size_t)s * H + L * 4);
            }
            j[p] = jj + 2;
        }
        #pragma unroll
        for (int q = 0; q < 8; ++q) if (act[q]) addb(a[q >> 1], v[q]);
    }
}

// ---- fused layer: bf16 h in/out, fp32 compute; optional fused mean-pool ----
__global__ __launch_bounds__(256, 6) void layer_both(
        const u16* __restrict__ hf_old, const u16* __restrict__ ha_old,
        u16* __restrict__ hf_new, u16* __restrict__ ha_new,
        const int* __restrict__ rpC, const int* __restrict__ colC,
        const int* __restrict__ rpU, const int* __restrict__ colU,
        const int* __restrict__ rpA, const int* __restrict__ colA,
        const float* __restrict__ wtr, const float* __restrict__ wtlc,
        const float* __restrict__ wtlu,
        const float* __restrict__ wtruse, const float* __restrict__ wtluse,
        const float* __restrict__ bias_c, const float* __restrict__ bias_u,
        const float* __restrict__ bias_a,
        float* __restrict__ psh)
{
    __shared__ __align__(16) float4 X[64 * 16];
    const int b = blockIdx.x;
    const int t = threadIdx.x;
    const int L = t & 15, g = t >> 4;
    const int og = t & 15, ng = t >> 4;
    const float4 z4 = make_float4(0.f, 0.f, 0.f, 0.f);

    float4 acc[4];
    #pragma unroll
    for (int j = 0; j < 4; ++j) acc[j] = z4;
    float4 o4[4];
    #pragma unroll
    for (int j = 0; j < 4; ++j) o4[j] = z4;

    if (b < NBF) {
        const int i0 = b * 64;
        {
            int j1[4], e1[4], d1[4]; float4 a1[4];
            #pragma unroll
            for (int p = 0; p < 4; ++p) {
                int node = i0 + p * 16 + g;
                j1[p] = rpC[node]; e1[p] = rpC[node + 1]; d1[p] = e1[p] - j1[p];
                a1[p] = z4;
            }
            gather8(hf_old, colC, j1, e1, L, a1);
            #pragma unroll
            for (int p = 0; p < 4; ++p) {
                int n = p * 16 + g;
                scl4(a1[p], 1.0f / (float)max(d1[p], 1));
                X[n * 16 + (L ^ ((n >> 2) & 7))] = a1[p];
            }
        }
        __syncthreads();
        gemm_acc(X, reinterpret_cast<const float4*>(wtlc), og, ng, acc);
        __syncthreads();
        {
            int j2[4], e2[4], d2[4]; float4 a2[4];
            #pragma unroll
            for (int p = 0; p < 4; ++p) {
                int node = i0 + p * 16 + g;
                j2[p] = rpU[node]; e2[p] = rpU[node + 1]; d2[p] = e2[p] - j2[p];
                a2[p] = z4;
            }
            gather8(ha_old, colU, j2, e2, L, a2);
            #pragma unroll
            for (int p = 0; p < 4; ++p) {
                int n = p * 16 + g;
                scl4(a2[p], 1.0f / (float)max(d2[p], 1));
                X[n * 16 + (L ^ ((n >> 2) & 7))] = a2[p];
            }
        }
        __syncthreads();
        ushort4 ow[4];
        #pragma unroll
        for (int r = 0; r < 4; ++r) {
            int idx = t + r * 256;
            int n = idx >> 4, k4 = idx & 15;
            ow[r] = *reinterpret_cast<const ushort4*>(hf_old + (size_t)(i0 + n) * H + k4 * 4);
        }
        gemm_acc(X, reinterpret_cast<const float4*>(wtlu), og, ng, acc);
        __syncthreads();
        #pragma unroll
        for (int r = 0; r < 4; ++r) {
            int idx = t + r * 256;
            int n = idx >> 4, k4 = idx & 15;
            X[n * 16 + (k4 ^ ((n >> 2) & 7))] = b2f4(ow[r]);
        }
        __syncthreads();
        gemm_acc(X, reinterpret_cast<const float4*>(wtr), og, ng, acc);
        float4 ba = reinterpret_cast<const float4*>(bias_c)[og];
        float4 bb = reinterpret_cast<const float4*>(bias_u)[og];
        float4 bv = make_float4(ba.x + bb.x, ba.y + bb.y, ba.z + bb.z, ba.w + bb.w);
        #pragma unroll
        for (int j = 0; j < 4; ++j) {
            int node = i0 + ng * 4 + j;
            float4 o;
            o.x = fmaxf(acc[j].x + bv.x, 0.f);
            o.y = fmaxf(acc[j].y + bv.y, 0.f);
            o.z = fmaxf(acc[j].z + bv.z, 0.f);
            o.w = fmaxf(acc[j].w + bv.w, 0.f);
            o4[j] = o;
            *reinterpret_cast<ushort4*>(hf_new + (size_t)node * H + og * 4) = f2b4(o);
        }
        if (psh) {
            float4 s = z4;
            #pragma unroll
            for (int j = 0; j < 4; ++j) add4(s, o4[j]);
            __syncthreads();
            X[ng * 16 + og] = s;
            __syncthreads();
            if (ng == 0) {
                float4 tot = z4;
                #pragma unroll
                for (int q = 0; q < 16; ++q) add4(tot, X[q * 16 + og]);
                float* dst = psh + (size_t)(b & (NSHADOW - 1)) * 128 + og * 4;
                atomicAdd(dst + 0, tot.x); atomicAdd(dst + 1, tot.y);
                atomicAdd(dst + 2, tot.z); atomicAdd(dst + 3, tot.w);
            }
        }
    } else {
        const int i0 = (b - NBF) * 64;
        {
            int j1[4], e1[4], d1[4]; float4 a1[4];
            #pragma unroll
            for (int p = 0; p < 4; ++p) {
                int node = i0 + p * 16 + g;
                if (node < N_API) { j1[p] = rpA[node]; e1[p] = rpA[node + 1]; }
                else { j1[p] = 0; e1[p] = 0; }
                d1[p] = e1[p] - j1[p];
                a1[p] = z4;
            }
            gather8(hf_old, colA, j1, e1, L, a1);
            #pragma unroll
            for (int p = 0; p < 4; ++p) {
                int n = p * 16 + g;
                scl4(a1[p], 1.0f / (float)max(d1[p], 1));
                X[n * 16 + (L ^ ((n >> 2) & 7))] = a1[p];
            }
        }
        __syncthreads();
        ushort4 ow[4];
        #pragma unroll
        for (int r = 0; r < 4; ++r) {
            int idx = t + r * 256;
            int n = idx >> 4, k4 = idx & 15;
            int node = i0 + n;
            ow[r] = make_ushort4(0, 0, 0, 0);
            if (node < N_API)
                ow[r] = *reinterpret_cast<const ushort4*>(ha_old + (size_t)node * H + k4 * 4);
        }
        gemm_acc(X, reinterpret_cast<const float4*>(wtluse), og, ng, acc);
        __syncthreads();
        #pragma unroll
        for (int r = 0; r < 4; ++r) {
            int idx = t + r * 256;
            int n = idx >> 4, k4 = idx & 15;
            X[n * 16 + (k4 ^ ((n >> 2) & 7))] = b2f4(ow[r]);
        }
        __syncthreads();
        gemm_acc(X, reinterpret_cast<const float4*>(wtruse), og, ng, acc);
        float4 bv = reinterpret_cast<const float4*>(bias_a)[og];
        #pragma unroll
        for (int j = 0; j < 4; ++j) {
            int node = i0 + ng * 4 + j;
            if (node < N_API) {
                float4 o;
                o.x = fmaxf(acc[j].x + bv.x, 0.f);
                o.y = fmaxf(acc[j].y + bv.y, 0.f);
                o.z = fmaxf(acc[j].z + bv.z, 0.f);
                o.w = fmaxf(acc[j].w + bv.w, 0.f);
                o4[j] = o;
                *reinterpret_cast<ushort4*>(ha_new + (size_t)node * H + og * 4) = f2b4(o);
            }
        }
        if (psh) {
            float4 s = z4;
            #pragma unroll
            for (int j = 0; j < 4; ++j) add4(s, o4[j]);
            __syncthreads();
            X[ng * 16 + og] = s;
            __syncthreads();
            if (ng == 0) {
                float4 tot = z4;
                #pragma unroll
                for (int q = 0; q < 16; ++q) add4(tot, X[q * 16 + og]);
                float* dst = psh + (size_t)(b & (NSHADOW - 1)) * 128 + 64 + og * 4;
                atomicAdd(dst + 0, tot.x); atomicAdd(dst + 1, tot.y);
                atomicAdd(dst + 2, tot.z); atomicAdd(dst + 3, tot.w);
            }
        }
    }
}

__global__ __launch_bounds__(128) void classifier_kernel(const float* __restrict__ shadows,
        const float* __restrict__ Wc1, const float* __restrict__ bc1,
        const float* __restrict__ Wc2, const float* __restrict__ bc2,
        float* __restrict__ out)
{
    __shared__ float ps[128];
    __shared__ float z1[64];
    int t = threadIdx.x;
    float s = 0.f;
    for (int q = 0; q < NSHADOW; ++q) s += shadows[q * 128 + t];
    ps[t] = s * (t < 64 ? (1.0f / N_FUNC) : (1.0f / N_API));
    __syncthreads();
    if (t < 64) {
        float a = bc1[t];
        for (int k = 0; k < 128; ++k) a = fmaf(ps[k], Wc1[t * 128 + k], a);
        z1[t] = fmaxf(a, 0.f);
    }
    __syncthreads();
    if (t < 2) {
        float a = bc2[t];
        for (int j = 0; j < 64; ++j) a = fmaf(z1[j], Wc2[t * 64 + j], a);
        out[t] = a;
    }
}

extern "C" void kernel_launch(void* const* d_in, const int* in_sizes, int n_in,
                              void* d_out, int out_size, void* d_ws, size_t ws_size,
                              hipStream_t stream)
{
    const float* x_func    = (const float*)d_in[0];
    const float* x_api     = (const float*)d_in[1];
    const float* w_in_func = (const float*)d_in[2];
    const float* b_in_func = (const float*)d_in[3];
    const float* w_in_api  = (const float*)d_in[4];
    const float* b_in_api  = (const float*)d_in[5];
    const float* Wl_calls  = (const float*)d_in[6];
    const float* bl_calls  = (const float*)d_in[7];
    const float* Wr_calls  = (const float*)d_in[8];
    const float* Wl_uses   = (const float*)d_in[9];
    const float* bl_uses   = (const float*)d_in[10];
    const float* Wr_uses   = (const float*)d_in[11];
    const float* Wl_usedby = (const float*)d_in[12];
    const float* bl_usedby = (const float*)d_in[13];
    const float* Wr_usedby = (const float*)d_in[14];
    const float* Wc1       = (const float*)d_in[15];
    const float* bc1       = (const float*)d_in[16];
    const float* Wc2       = (const float*)d_in[17];
    const float* bc2       = (const float*)d_in[18];
    const int*   ei_calls  = (const int*)d_in[19];
    const int*   ei_uses   = (const int*)d_in[20];
    const int*   ei_usedby = (const int*)d_in[21];
    const int E = in_sizes[19] / 2;

    float* ws = (float*)d_ws;
    size_t off = 0;
    u16* hf0 = (u16*)(ws + off); off += (size_t)N_FUNC * 32;
    u16* hf1 = (u16*)(ws + off); off += (size_t)N_FUNC * 32;
    u16* ha0 = (u16*)(ws + off); off += (size_t)N_API * 32;
    u16* ha1 = (u16*)(ws + off); off += (size_t)N_API * 32;
    float* prep = ws + off; off += 12288 + 10 * 4096;
    int* bktC = (int*)(ws + off); off += NBK;
    int* bktU = (int*)(ws + off); off += NBK;
    int* bktA = (int*)(ws + off); off += NBK;
    float* shadows = ws + off; off += NSHADOW * 128;
    int* bbC = (int*)(ws + off); off += NBK;
    int* bbU = (int*)(ws + off); off += NBK;
    int* bbA = (int*)(ws + off); off += NBK;
    int* rpC = (int*)(ws + off); off += N_FUNC + 1;
    int* rpU = (int*)(ws + off); off += N_FUNC + 1;
    int* rpA = (int*)(ws + off); off += N_API + 1;
    int* colC = (int*)(ws + off); off += E;
    int* colU = (int*)(ws + off); off += E;
    int* colA = (int*)(ws + off); off += E;
    int* beC = (int*)(ws + off); off += (size_t)NBK * BCAP;
    int* beU = (int*)(ws + off); off += (size_t)NBK * BCAP;
    int* beA = (int*)(ws + off); off += (size_t)NBK * BCAP;

    const int nbPerRel = (E + EPB - 1) / EPB;

    hipMemsetAsync(bktC, 0, (size_t)(3 * NBK + NSHADOW * 128) * sizeof(float), stream);

    prep_and_binA<<<PREPB + 3 * nbPerRel, 256, 0, stream>>>(
            w_in_func, w_in_api, Wl_calls, Wr_calls, Wl_uses, Wr_uses,
            Wl_usedby, Wr_usedby, prep,
            ei_calls, ei_calls + E, ei_usedby, ei_usedby + E, ei_uses, ei_uses + E,
            bktC, bktU, bktA, beC, beU, beA, E, nbPerRel);

    scan_buckets<<<1, 256, 0, stream>>>(bktC, bktU, bktA, bbC, bbU, bbA);

    float* wt_in_func = prep;
    float* wt_in_api  = prep + 8192;
    float* wt_r[NLAYERS], *wt_lc[NLAYERS], *wt_lu[NLAYERS], *wt_luse[NLAYERS], *wt_ruse[NLAYERS];
    for (int l = 0; l < NLAYERS; ++l) {
        wt_r[l]    = prep + 12288 + (l * 5 + 0) * 4096;
        wt_lc[l]   = prep + 12288 + (l * 5 + 1) * 4096;
        wt_lu[l]   = prep + 12288 + (l * 5 + 2) * 4096;
        wt_luse[l] = prep + 12288 + (l * 5 + 3) * 4096;
        wt_ruse[l] = prep + 12288 + (l * 5 + 4) * 4096;
    }

    binB_and_proj<<<3 * NBK + NBF + NBA, 256, 0, stream>>>(
            beC, beU, beA, bktC, bktU, bktA, bbC, bbU, bbA,
            rpC, rpU, rpA, colC, colU, colA,
            x_func, wt_in_func, b_in_func, hf0,
            x_api, wt_in_api, b_in_api, ha0);

    u16* hf[2] = { hf0, hf1 };
    u16* ha[2] = { ha0, ha1 };
    for (int l = 0; l < NLAYERS; ++l) {
        int cur = l & 1, nxt = cur ^ 1;
        layer_both<<<NBF + NBA, 256, 0, stream>>>(
                hf[cur], ha[cur], hf[nxt], ha[nxt],
                rpC, colC, rpU, colU, rpA, colA,
                wt_r[l], wt_lc[l], wt_lu[l], wt_ruse[l], wt_luse[l],
                bl_calls + l * 64, bl_usedby + l * 64, bl_uses + l * 64,
                (l == NLAYERS - 1) ? shadows : nullptr);
    }

    classifier_kernel<<<1, 128, 0, stream>>>(shadows, Wc1, bc1, Wc2, bc2, (float*)d_out);
}

// Round 12
// 351.358 us; speedup vs baseline: 1.6026x; 1.1817x over previous
//
#include <hip/hip_runtime.h>

#define N_FUNC 200000
#define N_API  50000
#define H      64
#define NLAYERS 2
#define NBF 3125   // N_FUNC/64 exact
#define NBA 782    // ceil(N_API/64)
#define PREPB 208  // ceil(53248/256) weight-prep blocks
#define NSHADOW 64
#define NBK   391  // buckets per relation
#define BCAP  4096
#define EPB   4096
#define WLOG_F 9
#define WLOG_A 7
#define SCAP  192  // staged edge rows per chunk (24KB)

typedef unsigned short u16;
typedef unsigned int u32;

__device__ __forceinline__ void fma4(float4& a, float s, float4 w) {
    a.x = fmaf(s, w.x, a.x); a.y = fmaf(s, w.y, a.y);
    a.z = fmaf(s, w.z, a.z); a.w = fmaf(s, w.w, a.w);
}
__device__ __forceinline__ void add4(float4& a, float4 v) {
    a.x += v.x; a.y += v.y; a.z += v.z; a.w += v.w;
}
__device__ __forceinline__ void scl4(float4& a, float s) {
    a.x *= s; a.y *= s; a.z *= s; a.w *= s;
}
__device__ __forceinline__ float bf2f(u16 u) {
    return __uint_as_float(((unsigned int)u) << 16);
}
__device__ __forceinline__ u16 f2bf(float f) {
    unsigned int x = __float_as_uint(f);
    return (u16)((x + 0x7FFFu + ((x >> 16) & 1u)) >> 16);
}
__device__ __forceinline__ float4 b2f4(ushort4 v) {
    return make_float4(bf2f(v.x), bf2f(v.y), bf2f(v.z), bf2f(v.w));
}
__device__ __forceinline__ ushort4 f2b4(float4 o) {
    ushort4 r; r.x = f2bf(o.x); r.y = f2bf(o.y); r.z = f2bf(o.z); r.w = f2bf(o.w);
    return r;
}
__device__ __forceinline__ void addb(float4& a, ushort4 v) {
    a.x += bf2f(v.x); a.y += bf2f(v.y); a.z += bf2f(v.z); a.w += bf2f(v.w);
}

// ==== K1: weight prep + binA bucket-scatter (unchanged from r11) ====
__global__ __launch_bounds__(256, 6) void prep_and_binA(
        const float* __restrict__ w_in_func, const float* __restrict__ w_in_api,
        const float* __restrict__ Wl_calls, const float* __restrict__ Wr_calls,
        const float* __restrict__ Wl_uses,  const float* __restrict__ Wr_uses,
        const float* __restrict__ Wl_usedby,const float* __restrict__ Wr_usedby,
        float* __restrict__ out,
        const int* __restrict__ sC, const int* __restrict__ dC,
        const int* __restrict__ sU, const int* __restrict__ dU,
        const int* __restrict__ sA, const int* __restrict__ dA,
        int* __restrict__ bktC, int* __restrict__ bktU, int* __restrict__ bktA,
        int* __restrict__ beC, int* __restrict__ beU, int* __restrict__ beA,
        int E, int nbPerRel)
{
    __shared__ int staged[EPB];
    __shared__ int hist[NBK + 1];
    __shared__ int lcnt[NBK];
    __shared__ int gbase[NBK];
    __shared__ int stemp[256];
    const int b = blockIdx.x, t = threadIdx.x;
    if (b < PREPB) {
        int idx = b * 256 + t;
        if (idx < 8192) {
            int k = idx >> 6, o = idx & 63;
            out[idx] = w_in_func[o * 128 + k];
        } else if (idx < 12288) {
            int r = idx - 8192; int k = r >> 6, o = r & 63;
            out[idx] = w_in_api[o * 64 + k];
        } else if (idx < 12288 + 10 * 4096) {
            int r = idx - 12288;
            int m = r >> 12, w = r & 4095;
            int k = w >> 6, o = w & 63;
            int l = m / 5, which = m - 5 * l;
            const float* A; const float* B = nullptr;
            if (which == 0)      { A = Wr_calls  + l * 4096; B = Wr_usedby + l * 4096; }
            else if (which == 1)   A = Wl_calls  + l * 4096;
            else if (which == 2)   A = Wl_usedby + l * 4096;
            else if (which == 3)   A = Wl_uses   + l * 4096;
            else                   A = Wr_uses   + l * 4096;
            float v = A[o * 64 + k];
            if (B) v += B[o * 64 + k];
            out[idx] = v;
        }
        return;
    }
    int bb = b - PREPB;
    int rel = bb / nbPerRel, lb = bb - rel * nbPerRel;
    const int* srcA; const int* dstA; int* bcnt; int* be; int wlog;
    if (rel == 0)      { srcA = sC; dstA = dC; bcnt = bktC; be = beC; wlog = WLOG_F; }
    else if (rel == 1) { srcA = sU; dstA = dU; bcnt = bktU; be = beU; wlog = WLOG_F; }
    else               { srcA = sA; dstA = dA; bcnt = bktA; be = beA; wlog = WLOG_A; }
    const int mask = (1 << wlog) - 1;
    const int e0 = lb * EPB;
    const int cnt = min(EPB, E - e0);
    for (int i = t; i < NBK; i += 256) { hist[i] = 0; lcnt[i] = 0; }
    __syncthreads();
    for (int i = t; i < cnt; i += 256)
        atomicAdd(&hist[dstA[e0 + i] >> wlog], 1);
    __syncthreads();
    int v0 = (2 * t < NBK) ? hist[2 * t] : 0;
    int v1 = (2 * t + 1 < NBK) ? hist[2 * t + 1] : 0;
    __syncthreads();
    stemp[t] = v0 + v1; __syncthreads();
    for (int s = 1; s < 256; s <<= 1) {
        int x = (t >= s) ? stemp[t - s] : 0;
        __syncthreads(); stemp[t] += x; __syncthreads();
    }
    int base = (t > 0) ? stemp[t - 1] : 0;
    if (2 * t < NBK)     hist[2 * t] = base;
    if (2 * t + 1 < NBK) hist[2 * t + 1] = base + v0;
    if (t == 255) hist[NBK] = stemp[255];
    __syncthreads();
    for (int i = t; i < cnt; i += 256) {
        int d = dstA[e0 + i], s = srcA[e0 + i];
        int bin = d >> wlog;
        int loc = atomicAdd(&lcnt[bin], 1);
        staged[hist[bin] + loc] = (s << wlog) | (d & mask);
    }
    __syncthreads();
    for (int i = t; i < NBK; i += 256) {
        int c = hist[i + 1] - hist[i];
        gbase[i] = (c > 0) ? atomicAdd(&bcnt[i], c) : 0;
    }
    __syncthreads();
    int wv = t >> 6, ln = t & 63;
    for (int bin = wv; bin < NBK; bin += 4) {
        int l0 = hist[bin], c = hist[bin + 1] - l0;
        int gb = gbase[bin];
        for (int k = ln; k < c; k += 64)
            if (gb + k < BCAP)
                be[(size_t)bin * BCAP + gb + k] = staged[l0 + k];
    }
}

// ==== K2: exclusive scan of 3x391 bucket counts ====
__global__ __launch_bounds__(256) void scan_buckets(
        const int* __restrict__ bktC, const int* __restrict__ bktU, const int* __restrict__ bktA,
        int* __restrict__ bbC, int* __restrict__ bbU, int* __restrict__ bbA)
{
    __shared__ int st[256];
    int t = threadIdx.x;
    for (int r = 0; r < 3; ++r) {
        const int* c = (r == 0) ? bktC : (r == 1) ? bktU : bktA;
        int* B = (r == 0) ? bbC : (r == 1) ? bbU : bbA;
        int v0 = (2 * t < NBK) ? min(c[2 * t], BCAP) : 0;
        int v1 = (2 * t + 1 < NBK) ? min(c[2 * t + 1], BCAP) : 0;
        st[t] = v0 + v1; __syncthreads();
        for (int s = 1; s < 256; s <<= 1) {
            int x = (t >= s) ? st[t - s] : 0;
            __syncthreads(); st[t] += x; __syncthreads();
        }
        int base = (t > 0) ? st[t - 1] : 0;
        if (2 * t < NBK)     B[2 * t] = base;
        if (2 * t + 1 < NBK) B[2 * t + 1] = base + v0;
        __syncthreads();
    }
}

// ---- GEMM-accumulate over 64x64 LDS tile (XOR-swizzled) ----
__device__ __forceinline__ void gemm_acc(const float4* X, const float4* __restrict__ wt4,
        int og, int ng, float4 acc[4])
{
    for (int k4 = 0; k4 < 16; ++k4) {
        float4 w0 = wt4[(4 * k4 + 0) * 16 + og];
        float4 w1 = wt4[(4 * k4 + 1) * 16 + og];
        float4 w2 = wt4[(4 * k4 + 2) * 16 + og];
        float4 w3 = wt4[(4 * k4 + 3) * 16 + og];
        #pragma unroll
        for (int j = 0; j < 4; ++j) {
            int n = ng * 4 + j;
            float4 xv = X[n * 16 + (k4 ^ ((n >> 2) & 7))];
            fma4(acc[j], xv.x, w0); fma4(acc[j], xv.y, w1);
            fma4(acc[j], xv.z, w2); fma4(acc[j], xv.w, w3);
        }
    }
}

// ---- proj bodies (16KB LDS); h output bf16 (unchanged) ----
__device__ __forceinline__ void proj_body128(const float* __restrict__ x,
        const float* __restrict__ wt, const float* __restrict__ bias,
        u16* __restrict__ hout, int i0, float4* smem)
{
    const int t = threadIdx.x;
    const int og = t & 15, ng = t >> 4;
    float4 acc[4];
    #pragma unroll
    for (int j = 0; j < 4; ++j) acc[j] = make_float4(0.f, 0.f, 0.f, 0.f);
    const float4* w4 = reinterpret_cast<const float4*>(wt);
    #pragma unroll
    for (int ph = 0; ph < 2; ++ph) {
        if (ph) __syncthreads();
        for (int idx = t; idx < 1024; idx += 256) {
            int n = idx >> 4, k4 = idx & 15;
            smem[n * 16 + (k4 ^ ((n >> 2) & 7))] =
                *reinterpret_cast<const float4*>(x + (size_t)(i0 + n) * 128 + ph * 64 + k4 * 4);
        }
        __syncthreads();
        gemm_acc(smem, w4 + ph * 1024, og, ng, acc);
    }
    float4 b = reinterpret_cast<const float4*>(bias)[og];
    #pragma unroll
    for (int j = 0; j < 4; ++j) {
        int node = i0 + ng * 4 + j;
        float4 o;
        o.x = fmaxf(acc[j].x + b.x, 0.f);
        o.y = fmaxf(acc[j].y + b.y, 0.f);
        o.z = fmaxf(acc[j].z + b.z, 0.f);
        o.w = fmaxf(acc[j].w + b.w, 0.f);
        *reinterpret_cast<ushort4*>(hout + (size_t)node * H + og * 4) = f2b4(o);
    }
}

__device__ __forceinline__ void proj_body64(const float* __restrict__ x,
        const float* __restrict__ wt, const float* __restrict__ bias,
        u16* __restrict__ hout, int i0, int nN, float4* smem)
{
    const int t = threadIdx.x;
    for (int idx = t; idx < 1024; idx += 256) {
        int n = idx >> 4, k4 = idx & 15;
        float4 v = make_float4(0.f, 0.f, 0.f, 0.f);
        if (i0 + n < nN)
            v = *reinterpret_cast<const float4*>(x + (size_t)(i0 + n) * 64 + k4 * 4);
        smem[n * 16 + (k4 ^ ((n >> 2) & 7))] = v;
    }
    __syncthreads();
    const int og = t & 15, ng = t >> 4;
    float4 acc[4];
    #pragma unroll
    for (int j = 0; j < 4; ++j) acc[j] = make_float4(0.f, 0.f, 0.f, 0.f);
    gemm_acc(smem, reinterpret_cast<const float4*>(wt), og, ng, acc);
    float4 b = reinterpret_cast<const float4*>(bias)[og];
    #pragma unroll
    for (int j = 0; j < 4; ++j) {
        int node = i0 + ng * 4 + j;
        if (node < nN) {
            float4 o;
            o.x = fmaxf(acc[j].x + b.x, 0.f);
            o.y = fmaxf(acc[j].y + b.y, 0.f);
            o.z = fmaxf(acc[j].z + b.z, 0.f);
            o.w = fmaxf(acc[j].w + b.w, 0.f);
            *reinterpret_cast<ushort4*>(hout + (size_t)node * H + og * 4) = f2b4(o);
        }
    }
}

// ==== K3: binB (per-bucket local CSR) + both projections (unchanged) ====
__global__ __launch_bounds__(256, 6) void binB_and_proj(
        const int* __restrict__ beC, const int* __restrict__ beU, const int* __restrict__ beA,
        const int* __restrict__ bktC, const int* __restrict__ bktU, const int* __restrict__ bktA,
        const int* __restrict__ bbC, const int* __restrict__ bbU, const int* __restrict__ bbA,
        int* __restrict__ rpC, int* __restrict__ rpU, int* __restrict__ rpA,
        int* __restrict__ colC, int* __restrict__ colU, int* __restrict__ colA,
        const float* __restrict__ xf, const float* __restrict__ wtf,
        const float* __restrict__ bf, u16* __restrict__ hf,
        const float* __restrict__ xa, const float* __restrict__ wta,
        const float* __restrict__ ba_, u16* __restrict__ ha)
{
    __shared__ __align__(16) int shraw[BCAP + 513 + 512];
    const int b = blockIdx.x, t = threadIdx.x;
    if (b < 3 * NBK) {
        int rel = b / NBK, bkt = b - rel * NBK;
        const int* be; const int* bc; const int* bbs; int* rp; int* col; int wlog, n;
        if (rel == 0)      { be = beC; bc = bktC; bbs = bbC; rp = rpC; col = colC; wlog = WLOG_F; n = N_FUNC; }
        else if (rel == 1) { be = beU; bc = bktU; bbs = bbU; rp = rpU; col = colU; wlog = WLOG_F; n = N_FUNC; }
        else               { be = beA; bc = bktA; bbs = bbA; rp = rpA; col = colA; wlog = WLOG_A; n = N_API; }
        const int width = 1 << wlog, mask = width - 1;
        const int nodeBase = bkt << wlog;
        const int nN = min(width, n - nodeBase);
        const int cnt = min(bc[bkt], BCAP);
        const int gb = bbs[bkt];
        int* colS = shraw;
        int* lrp  = shraw + BCAP;
        int* nxL  = shraw + BCAP + 513;
        for (int i = t; i <= 512; i += 256) { lrp[i] = 0; if (i < 512) nxL[i] = 0; }
        __syncthreads();
        const int* bePtr = be + (size_t)bkt * BCAP;
        for (int i = t; i < cnt; i += 256)
            atomicAdd(&lrp[bePtr[i] & mask], 1);
        __syncthreads();
        int v0 = lrp[2 * t], v1 = lrp[2 * t + 1];
        __syncthreads();
        int* st = colS;
        st[t] = v0 + v1; __syncthreads();
        for (int s = 1; s < 256; s <<= 1) {
            int x = (t >= s) ? st[t - s] : 0;
            __syncthreads(); st[t] += x; __syncthreads();
        }
        int base0 = (t > 0) ? st[t - 1] : 0;
        lrp[2 * t] = base0; lrp[2 * t + 1] = base0 + v0;
        if (t == 255) lrp[512] = st[255];
        __syncthreads();
        for (int i = t; i < nN; i += 256) rp[nodeBase + i] = gb + lrp[i];
        if (nodeBase + nN == n && t == 0) rp[n] = gb + lrp[nN];
        __syncthreads();
        for (int i = t; i < cnt; i += 256) {
            int en = bePtr[i]; int dl = en & mask;
            int pos = lrp[dl] + atomicAdd(&nxL[dl], 1);
            colS[pos] = en >> wlog;
        }
        __syncthreads();
        for (int i = t; i < cnt; i += 256) col[gb + i] = colS[i];
    } else {
        int b2 = b - 3 * NBK;
        float4* smem = reinterpret_cast<float4*>(shraw);
        if (b2 < NBF) proj_body128(xf, wtf, bf, hf, b2 * 64, smem);
        else          proj_body64(xa, wta, ba_, ha, (b2 - NBF) * 64, N_API, smem);
    }
}

// ---- async DMA: stage rows [c0,c1) of src (via col, or identity if col==nullptr) ----
// 8 rows per instruction: 64 lanes x 16B; LDS dest linear (wave-uniform base).
__device__ __forceinline__ void issue_rows(const u16* __restrict__ src_h,
        const int* __restrict__ col, int c0, int c1, u16* stage, int t)
{
    const int w = t >> 6, lane = t & 63;
    const int cnt = c1 - c0;
    for (int le0 = w * 8; le0 < cnt; le0 += 32) {
        int ge = c0 + min(le0 + (lane >> 3), cnt - 1);   // clamp tail (garbage rows unread)
        int srow = col ? col[ge] : ge;
        const u16* gp = src_h + (size_t)srow * H + (lane & 7) * 8;
        __builtin_amdgcn_global_load_lds(
            (const __attribute__((address_space(1))) u32*)gp,
            (__attribute__((address_space(3))) u32*)(stage + le0 * 64),
            16, 0, 0);
    }
}

// consume staged rows for this thread's 4 nodes, window [c0,c1)
__device__ __forceinline__ void consume_rows(const u16* stage, const int s4[4],
        const int e4[4], int c0, int c1, int L, float4 acc[4])
{
    #pragma unroll
    for (int p = 0; p < 4; ++p) {
        int jlo = max(s4[p], c0), jhi = min(e4[p], c1);
        for (int j = jlo; j < jhi; ++j) {
            ushort4 v = *reinterpret_cast<const ushort4*>(stage + (size_t)(j - c0) * 64 + L * 4);
            addb(acc[p], v);
        }
    }
}

// ---- fused layer: DMA-staged gather + 3 GEMMs; fused mean-pool on last layer ----
__global__ __launch_bounds__(256, 4) void layer_both(
        const u16* __restrict__ hf_old, const u16* __restrict__ ha_old,
        u16* __restrict__ hf_new, u16* __restrict__ ha_new,
        const int* __restrict__ rpC, const int* __restrict__ colC,
        const int* __restrict__ rpU, const int* __restrict__ colU,
        const int* __restrict__ rpA, const int* __restrict__ colA,
        const float* __restrict__ wtr, const float* __restrict__ wtlc,
        const float* __restrict__ wtlu,
        const float* __restrict__ wtruse, const float* __restrict__ wtluse,
        const float* __restrict__ bias_c, const float* __restrict__ bias_u,
        const float* __restrict__ bias_a,
        float* __restrict__ psh)
{
    __shared__ __align__(16) float4 X[64 * 16];       // 16 KB
    __shared__ __align__(16) u16 stage[SCAP * 64];    // 24 KB
    const int b = blockIdx.x;
    const int t = threadIdx.x;
    const int L = t & 15, g = t >> 4;
    const int og = t & 15, ng = t >> 4;
    const float4 z4 = make_float4(0.f, 0.f, 0.f, 0.f);

    float4 acc[4];
    #pragma unroll
    for (int j = 0; j < 4; ++j) acc[j] = z4;
    float4 o4[4];
    #pragma unroll
    for (int j = 0; j < 4; ++j) o4[j] = z4;

    if (b < NBF) {
        const int i0 = b * 64;
        // node edge windows (calls)
        int s1[4], e1[4];
        #pragma unroll
        for (int p = 0; p < 4; ++p) {
            int node = i0 + p * 16 + g;
            s1[p] = rpC[node]; e1[p] = rpC[node + 1];
        }
        const int be0 = rpC[i0], be1 = rpC[i0 + 64];
        // ---- P1: calls gather (chunked DMA) ----
        float4 a1[4];
        #pragma unroll
        for (int p = 0; p < 4; ++p) a1[p] = z4;
        for (int c0 = be0; c0 < be1; c0 += SCAP) {
            int c1 = min(c0 + SCAP, be1);
            issue_rows(hf_old, colC, c0, c1, stage, t);
            __syncthreads();                       // drains vmcnt + sync
            consume_rows(stage, s1, e1, c0, c1, L, a1);
            __syncthreads();                       // stage free
        }
        // write X <- mean(calls)
        #pragma unroll
        for (int p = 0; p < 4; ++p) {
            int n = p * 16 + g;
            scl4(a1[p], 1.0f / (float)max(e1[p] - s1[p], 1));
            X[n * 16 + (L ^ ((n >> 2) & 7))] = a1[p];
        }
        __syncthreads();
        // ---- issue P2 (usedby) chunk-0 DMA; gemm1 hides flight ----
        int s2[4], e2[4];
        #pragma unroll
        for (int p = 0; p < 4; ++p) {
            int node = i0 + p * 16 + g;
            s2[p] = rpU[node]; e2[p] = rpU[node + 1];
        }
        const int ue0 = rpU[i0], ue1 = rpU[i0 + 64];
        int uc1 = min(ue0 + SCAP, ue1);
        if (ue1 > ue0) issue_rows(ha_old, colU, ue0, uc1, stage, t);
        gemm_acc(X, reinterpret_cast<const float4*>(wtlc), og, ng, acc);
        __syncthreads();                           // drains P2 DMA
        // ---- P2 consume (+ rare extra chunks) ----
        float4 a2[4];
        #pragma unroll
        for (int p = 0; p < 4; ++p) a2[p] = z4;
        if (ue1 > ue0) consume_rows(stage, s2, e2, ue0, uc1, L, a2);
        for (int c0 = uc1; c0 < ue1; c0 += SCAP) {
            int c1 = min(c0 + SCAP, ue1);
            __syncthreads();
            issue_rows(ha_old, colU, c0, c1, stage, t);
            __syncthreads();
            consume_rows(stage, s2, e2, c0, c1, L, a2);
        }
        __syncthreads();                           // stage reads done
        #pragma unroll
        for (int p = 0; p < 4; ++p) {
            int n = p * 16 + g;
            scl4(a2[p], 1.0f / (float)max(e2[p] - s2[p], 1));
            X[n * 16 + (L ^ ((n >> 2) & 7))] = a2[p];
        }
        __syncthreads();
        // ---- issue P3 (own rows) DMA; gemm2 hides flight ----
        issue_rows(hf_old, nullptr, i0, i0 + 64, stage, t);
        gemm_acc(X, reinterpret_cast<const float4*>(wtlu), og, ng, acc);
        __syncthreads();                           // drains P3 DMA
        // own rows stage -> X
        #pragma unroll
        for (int r = 0; r < 4; ++r) {
            int idx = t + r * 256;
            int n = idx >> 4, k4 = idx & 15;
            ushort4 v = *reinterpret_cast<const ushort4*>(stage + (size_t)n * 64 + k4 * 4);
            X[n * 16 + (k4 ^ ((n >> 2) & 7))] = b2f4(v);
        }
        __syncthreads();
        gemm_acc(X, reinterpret_cast<const float4*>(wtr), og, ng, acc);
        // ---- epilogue ----
        float4 ba = reinterpret_cast<const float4*>(bias_c)[og];
        float4 bb = reinterpret_cast<const float4*>(bias_u)[og];
        float4 bv = make_float4(ba.x + bb.x, ba.y + bb.y, ba.z + bb.z, ba.w + bb.w);
        #pragma unroll
        for (int j = 0; j < 4; ++j) {
            int node = i0 + ng * 4 + j;
            float4 o;
            o.x = fmaxf(acc[j].x + bv.x, 0.f);
            o.y = fmaxf(acc[j].y + bv.y, 0.f);
            o.z = fmaxf(acc[j].z + bv.z, 0.f);
            o.w = fmaxf(acc[j].w + bv.w, 0.f);
            o4[j] = o;
            *reinterpret_cast<ushort4*>(hf_new + (size_t)node * H + og * 4) = f2b4(o);
        }
        if (psh) {
            float4 s = z4;
            #pragma unroll
            for (int j = 0; j < 4; ++j) add4(s, o4[j]);
            __syncthreads();
            X[ng * 16 + og] = s;
            __syncthreads();
            if (ng == 0) {
                float4 tot = z4;
                #pragma unroll
                for (int q = 0; q < 16; ++q) add4(tot, X[q * 16 + og]);
                float* dst = psh + (size_t)(b & (NSHADOW - 1)) * 128 + og * 4;
                atomicAdd(dst + 0, tot.x); atomicAdd(dst + 1, tot.y);
                atomicAdd(dst + 2, tot.z); atomicAdd(dst + 3, tot.w);
            }
        }
    } else {
        const int i0 = (b - NBF) * 64;
        const int nTop = min(i0 + 64, N_API);
        int s1[4], e1[4];
        #pragma unroll
        for (int p = 0; p < 4; ++p) {
            int node = i0 + p * 16 + g;
            if (node < N_API) { s1[p] = rpA[node]; e1[p] = rpA[node + 1]; }
            else { s1[p] = 0; e1[p] = 0; }
        }
        const int be0 = rpA[i0], be1 = rpA[nTop];
        // ---- P1: uses gather (chunked DMA, ~3 chunks) ----
        float4 a1[4];
        #pragma unroll
        for (int p = 0; p < 4; ++p) a1[p] = z4;
        for (int c0 = be0; c0 < be1; c0 += SCAP) {
            int c1 = min(c0 + SCAP, be1);
            issue_rows(hf_old, colA, c0, c1, stage, t);
            __syncthreads();
            consume_rows(stage, s1, e1, c0, c1, L, a1);
            __syncthreads();
        }
        #pragma unroll
        for (int p = 0; p < 4; ++p) {
            int n = p * 16 + g;
            scl4(a1[p], 1.0f / (float)max(e1[p] - s1[p], 1));
            X[n * 16 + (L ^ ((n >> 2) & 7))] = a1[p];
        }
        __syncthreads();
        // ---- issue own rows DMA; gemm1 hides ----
        issue_rows(ha_old, nullptr, i0, nTop, stage, t);
        gemm_acc(X, reinterpret_cast<const float4*>(wtluse), og, ng, acc);
        __syncthreads();
        #pragma unroll
        for (int r = 0; r < 4; ++r) {
            int idx = t + r * 256;
            int n = idx >> 4, k4 = idx & 15;
            float4 xv = z4;
            if (i0 + n < N_API) {
                ushort4 v = *reinterpret_cast<const ushort4*>(stage + (size_t)n * 64 + k4 * 4);
                xv = b2f4(v);
            }
            X[n * 16 + (k4 ^ ((n >> 2) & 7))] = xv;
        }
        __syncthreads();
        gemm_acc(X, reinterpret_cast<const float4*>(wtruse), og, ng, acc);
        float4 bv = reinterpret_cast<const float4*>(bias_a)[og];
        #pragma unroll
        for (int j = 0; j < 4; ++j) {
            int node = i0 + ng * 4 + j;
            if (node < N_API) {
                float4 o;
                o.x = fmaxf(acc[j].x + bv.x, 0.f);
                o.y = fmaxf(acc[j].y + bv.y, 0.f);
                o.z = fmaxf(acc[j].z + bv.z, 0.f);
                o.w = fmaxf(acc[j].w + bv.w, 0.f);
                o4[j] = o;
                *reinterpret_cast<ushort4*>(ha_new + (size_t)node * H + og * 4) = f2b4(o);
            }
        }
        if (psh) {
            float4 s = z4;
            #pragma unroll
            for (int j = 0; j < 4; ++j) add4(s, o4[j]);
            __syncthreads();
            X[ng * 16 + og] = s;
            __syncthreads();
            if (ng == 0) {
                float4 tot = z4;
                #pragma unroll
                for (int q = 0; q < 16; ++q) add4(tot, X[q * 16 + og]);
                float* dst = psh + (size_t)(b & (NSHADOW - 1)) * 128 + 64 + og * 4;
                atomicAdd(dst + 0, tot.x); atomicAdd(dst + 1, tot.y);
                atomicAdd(dst + 2, tot.z); atomicAdd(dst + 3, tot.w);
            }
        }
    }
}

__global__ __launch_bounds__(128) void classifier_kernel(const float* __restrict__ shadows,
        const float* __restrict__ Wc1, const float* __restrict__ bc1,
        const float* __restrict__ Wc2, const float* __restrict__ bc2,
        float* __restrict__ out)
{
    __shared__ float ps[128];
    __shared__ float z1[64];
    int t = threadIdx.x;
    float s = 0.f;
    for (int q = 0; q < NSHADOW; ++q) s += shadows[q * 128 + t];
    ps[t] = s * (t < 64 ? (1.0f / N_FUNC) : (1.0f / N_API));
    __syncthreads();
    if (t < 64) {
        float a = bc1[t];
        for (int k = 0; k < 128; ++k) a = fmaf(ps[k], Wc1[t * 128 + k], a);
        z1[t] = fmaxf(a, 0.f);
    }
    __syncthreads();
    if (t < 2) {
        float a = bc2[t];
        for (int j = 0; j < 64; ++j) a = fmaf(z1[j], Wc2[t * 64 + j], a);
        out[t] = a;
    }
}

extern "C" void kernel_launch(void* const* d_in, const int* in_sizes, int n_in,
                              void* d_out, int out_size, void* d_ws, size_t ws_size,
                              hipStream_t stream)
{
    const float* x_func    = (const float*)d_in[0];
    const float* x_api     = (const float*)d_in[1];
    const float* w_in_func = (const float*)d_in[2];
    const float* b_in_func = (const float*)d_in[3];
    const float* w_in_api  = (const float*)d_in[4];
    const float* b_in_api  = (const float*)d_in[5];
    const float* Wl_calls  = (const float*)d_in[6];
    const float* bl_calls  = (const float*)d_in[7];
    const float* Wr_calls  = (const float*)d_in[8];
    const float* Wl_uses   = (const float*)d_in[9];
    const float* bl_uses   = (const float*)d_in[10];
    const float* Wr_uses   = (const float*)d_in[11];
    const float* Wl_usedby = (const float*)d_in[12];
    const float* bl_usedby = (const float*)d_in[13];
    const float* Wr_usedby = (const float*)d_in[14];
    const float* Wc1       = (const float*)d_in[15];
    const float* bc1       = (const float*)d_in[16];
    const float* Wc2       = (const float*)d_in[17];
    const float* bc2       = (const float*)d_in[18];
    const int*   ei_calls  = (const int*)d_in[19];
    const int*   ei_uses   = (const int*)d_in[20];
    const int*   ei_usedby = (const int*)d_in[21];
    const int E = in_sizes[19] / 2;

    float* ws = (float*)d_ws;
    size_t off = 0;
    u16* hf0 = (u16*)(ws + off); off += (size_t)N_FUNC * 32;
    u16* hf1 = (u16*)(ws + off); off += (size_t)N_FUNC * 32;
    u16* ha0 = (u16*)(ws + off); off += (size_t)N_API * 32;
    u16* ha1 = (u16*)(ws + off); off += (size_t)N_API * 32;
    float* prep = ws + off; off += 12288 + 10 * 4096;
    int* bktC = (int*)(ws + off); off += NBK;
    int* bktU = (int*)(ws + off); off += NBK;
    int* bktA = (int*)(ws + off); off += NBK;
    float* shadows = ws + off; off += NSHADOW * 128;
    int* bbC = (int*)(ws + off); off += NBK;
    int* bbU = (int*)(ws + off); off += NBK;
    int* bbA = (int*)(ws + off); off += NBK;
    int* rpC = (int*)(ws + off); off += N_FUNC + 1;
    int* rpU = (int*)(ws + off); off += N_FUNC + 1;
    int* rpA = (int*)(ws + off); off += N_API + 1;
    int* colC = (int*)(ws + off); off += E;
    int* colU = (int*)(ws + off); off += E;
    int* colA = (int*)(ws + off); off += E;
    int* beC = (int*)(ws + off); off += (size_t)NBK * BCAP;
    int* beU = (int*)(ws + off); off += (size_t)NBK * BCAP;
    int* beA = (int*)(ws + off); off += (size_t)NBK * BCAP;

    const int nbPerRel = (E + EPB - 1) / EPB;

    hipMemsetAsync(bktC, 0, (size_t)(3 * NBK + NSHADOW * 128) * sizeof(float), stream);

    prep_and_binA<<<PREPB + 3 * nbPerRel, 256, 0, stream>>>(
            w_in_func, w_in_api, Wl_calls, Wr_calls, Wl_uses, Wr_uses,
            Wl_usedby, Wr_usedby, prep,
            ei_calls, ei_calls + E, ei_usedby, ei_usedby + E, ei_uses, ei_uses + E,
            bktC, bktU, bktA, beC, beU, beA, E, nbPerRel);

    scan_buckets<<<1, 256, 0, stream>>>(bktC, bktU, bktA, bbC, bbU, bbA);

    float* wt_in_func = prep;
    float* wt_in_api  = prep + 8192;
    float* wt_r[NLAYERS], *wt_lc[NLAYERS], *wt_lu[NLAYERS], *wt_luse[NLAYERS], *wt_ruse[NLAYERS];
    for (int l = 0; l < NLAYERS; ++l) {
        wt_r[l]    = prep + 12288 + (l * 5 + 0) * 4096;
        wt_lc[l]   = prep + 12288 + (l * 5 + 1) * 4096;
        wt_lu[l]   = prep + 12288 + (l * 5 + 2) * 4096;
        wt_luse[l] = prep + 12288 + (l * 5 + 3) * 4096;
        wt_ruse[l] = prep + 12288 + (l * 5 + 4) * 4096;
    }

    binB_and_proj<<<3 * NBK + NBF + NBA, 256, 0, stream>>>(
            beC, beU, beA, bktC, bktU, bktA, bbC, bbU, bbA,
            rpC, rpU, rpA, colC, colU, colA,
            x_func, wt_in_func, b_in_func, hf0,
            x_api, wt_in_api, b_in_api, ha0);

    u16* hf[2] = { hf0, hf1 };
    u16* ha[2] = { ha0, ha1 };
    for (int l = 0; l < NLAYERS; ++l) {
        int cur = l & 1, nxt = cur ^ 1;
        layer_both<<<NBF + NBA, 256, 0, stream>>>(
                hf[cur], ha[cur], hf[nxt], ha[nxt],
                rpC, colC, rpU, colU, rpA, colA,
                wt_r[l], wt_lc[l], wt_lu[l], wt_ruse[l], wt_luse[l],
                bl_calls + l * 64, bl_usedby + l * 64, bl_uses + l * 64,
                (l == NLAYERS - 1) ? shadows : nullptr);
    }

    classifier_kernel<<<1, 128, 0, stream>>>(shadows, Wc1, bc1, Wc2, bc2, (float*)d_out);
}

// Round 13
// 243.828 us; speedup vs baseline: 2.3094x; 1.4410x over previous
//
#include <hip/hip_runtime.h>

#define N_FUNC 200000
#define N_API  50000
#define H      64
#define NLAYERS 2
#define NBF 3125   // N_FUNC/64 exact
#define NBA 782    // ceil(N_API/64)
#define PREPB 368  // ceil((12288 + 81920)/256)
#define NSHADOW 64
#define NBK   391  // buckets per relation
#define BCAP  4096
#define EPB   4096
#define WLOG_F 9
#define WLOG_A 7
#define SCAP  192  // staged edge rows per chunk (24KB)

typedef unsigned short u16;
typedef unsigned int u32;
typedef __bf16 bf16x8 __attribute__((ext_vector_type(8)));
typedef float f32x4 __attribute__((ext_vector_type(4)));

__device__ __forceinline__ void fma4(float4& a, float s, float4 w) {
    a.x = fmaf(s, w.x, a.x); a.y = fmaf(s, w.y, a.y);
    a.z = fmaf(s, w.z, a.z); a.w = fmaf(s, w.w, a.w);
}
__device__ __forceinline__ void add4(float4& a, float4 v) {
    a.x += v.x; a.y += v.y; a.z += v.z; a.w += v.w;
}
__device__ __forceinline__ void scl4(float4& a, float s) {
    a.x *= s; a.y *= s; a.z *= s; a.w *= s;
}
__device__ __forceinline__ float bf2f(u16 u) {
    return __uint_as_float(((unsigned int)u) << 16);
}
__device__ __forceinline__ u16 f2bf(float f) {   // RNE
    unsigned int x = __float_as_uint(f);
    return (u16)((x + 0x7FFFu + ((x >> 16) & 1u)) >> 16);
}
__device__ __forceinline__ float4 b2f4(ushort4 v) {
    return make_float4(bf2f(v.x), bf2f(v.y), bf2f(v.z), bf2f(v.w));
}
__device__ __forceinline__ ushort4 f2b4(float4 o) {
    ushort4 r; r.x = f2bf(o.x); r.y = f2bf(o.y); r.z = f2bf(o.z); r.w = f2bf(o.w);
    return r;
}
__device__ __forceinline__ void addb(float4& a, ushort4 v) {
    a.x += bf2f(v.x); a.y += bf2f(v.y); a.z += bf2f(v.z); a.w += bf2f(v.w);
}

// ==== K1: weight prep (proj fp32 + MFMA-packed hi/lo bf16) + binA bucket-scatter ====
// prep idx space: [0,8192) wt_in_func; [8192,12288) wt_in_api;
// [12288, 12288+81920): packed gemm weights, 10 matrices x {hi,lo} x 4096
__global__ __launch_bounds__(256, 6) void prep_and_binA(
        const float* __restrict__ w_in_func, const float* __restrict__ w_in_api,
        const float* __restrict__ Wl_calls, const float* __restrict__ Wr_calls,
        const float* __restrict__ Wl_uses,  const float* __restrict__ Wr_uses,
        const float* __restrict__ Wl_usedby,const float* __restrict__ Wr_usedby,
        float* __restrict__ outf, u16* __restrict__ wpk,
        const int* __restrict__ sC, const int* __restrict__ dC,
        const int* __restrict__ sU, const int* __restrict__ dU,
        const int* __restrict__ sA, const int* __restrict__ dA,
        int* __restrict__ bktC, int* __restrict__ bktU, int* __restrict__ bktA,
        int* __restrict__ beC, int* __restrict__ beU, int* __restrict__ beA,
        int E, int nbPerRel)
{
    __shared__ int staged[EPB];
    __shared__ int hist[NBK + 1];
    __shared__ int lcnt[NBK];
    __shared__ int gbase[NBK];
    __shared__ int stemp[256];
    const int b = blockIdx.x, t = threadIdx.x;
    if (b < PREPB) {
        int idx = b * 256 + t;
        if (idx < 8192) {
            int k = idx >> 6, o = idx & 63;
            outf[idx] = w_in_func[o * 128 + k];
        } else if (idx < 12288) {
            int r = idx - 8192; int k = r >> 6, o = r & 63;
            outf[idx] = w_in_api[o * 64 + k];
        } else if (idx < 12288 + 81920) {
            int r = idx - 12288;
            int m = r >> 13;            // matrix 0..9
            int w2 = r & 8191;
            int half = w2 >> 12;        // 0=hi 1=lo
            int w = w2 & 4095;
            int kt = w >> 11;
            int nt = (w >> 9) & 3;
            int lane = (w >> 3) & 63;
            int i = w & 7;
            int k = kt * 32 + (lane >> 4) * 8 + i;
            int n = nt * 16 + (lane & 15);
            int l = m / 5, which = m - 5 * l;
            const float* A; const float* B = nullptr;
            if (which == 0)      { A = Wr_calls  + l * 4096; B = Wr_usedby + l * 4096; }
            else if (which == 1)   A = Wl_calls  + l * 4096;
            else if (which == 2)   A = Wl_usedby + l * 4096;
            else if (which == 3)   A = Wl_uses   + l * 4096;
            else                   A = Wr_uses   + l * 4096;
            float v = A[n * 64 + k];
            if (B) v += B[n * 64 + k];
            u16 hi = f2bf(v);
            wpk[m * 8192 + half * 4096 + w] = half ? f2bf(v - bf2f(hi)) : hi;
        }
        return;
    }
    int bb = b - PREPB;
    int rel = bb / nbPerRel, lb = bb - rel * nbPerRel;
    const int* srcA; const int* dstA; int* bcnt; int* be; int wlog;
    if (rel == 0)      { srcA = sC; dstA = dC; bcnt = bktC; be = beC; wlog = WLOG_F; }
    else if (rel == 1) { srcA = sU; dstA = dU; bcnt = bktU; be = beU; wlog = WLOG_F; }
    else               { srcA = sA; dstA = dA; bcnt = bktA; be = beA; wlog = WLOG_A; }
    const int mask = (1 << wlog) - 1;
    const int e0 = lb * EPB;
    const int cnt = min(EPB, E - e0);
    for (int i = t; i < NBK; i += 256) { hist[i] = 0; lcnt[i] = 0; }
    __syncthreads();
    for (int i = t; i < cnt; i += 256)
        atomicAdd(&hist[dstA[e0 + i] >> wlog], 1);
    __syncthreads();
    int v0 = (2 * t < NBK) ? hist[2 * t] : 0;
    int v1 = (2 * t + 1 < NBK) ? hist[2 * t + 1] : 0;
    __syncthreads();
    stemp[t] = v0 + v1; __syncthreads();
    for (int s = 1; s < 256; s <<= 1) {
        int x = (t >= s) ? stemp[t - s] : 0;
        __syncthreads(); stemp[t] += x; __syncthreads();
    }
    int base = (t > 0) ? stemp[t - 1] : 0;
    if (2 * t < NBK)     hist[2 * t] = base;
    if (2 * t + 1 < NBK) hist[2 * t + 1] = base + v0;
    if (t == 255) hist[NBK] = stemp[255];
    __syncthreads();
    for (int i = t; i < cnt; i += 256) {
        int d = dstA[e0 + i], s = srcA[e0 + i];
        int bin = d >> wlog;
        int loc = atomicAdd(&lcnt[bin], 1);
        staged[hist[bin] + loc] = (s << wlog) | (d & mask);
    }
    __syncthreads();
    for (int i = t; i < NBK; i += 256) {
        int c = hist[i + 1] - hist[i];
        gbase[i] = (c > 0) ? atomicAdd(&bcnt[i], c) : 0;
    }
    __syncthreads();
    int wv = t >> 6, ln = t & 63;
    for (int bin = wv; bin < NBK; bin += 4) {
        int l0 = hist[bin], c = hist[bin + 1] - l0;
        int gb = gbase[bin];
        for (int k = ln; k < c; k += 64)
            if (gb + k < BCAP)
                be[(size_t)bin * BCAP + gb + k] = staged[l0 + k];
    }
}

// ==== K2: exclusive scan of 3x391 bucket counts ====
__global__ __launch_bounds__(256) void scan_buckets(
        const int* __restrict__ bktC, const int* __restrict__ bktU, const int* __restrict__ bktA,
        int* __restrict__ bbC, int* __restrict__ bbU, int* __restrict__ bbA)
{
    __shared__ int st[256];
    int t = threadIdx.x;
    for (int r = 0; r < 3; ++r) {
        const int* c = (r == 0) ? bktC : (r == 1) ? bktU : bktA;
        int* B = (r == 0) ? bbC : (r == 1) ? bbU : bbA;
        int v0 = (2 * t < NBK) ? min(c[2 * t], BCAP) : 0;
        int v1 = (2 * t + 1 < NBK) ? min(c[2 * t + 1], BCAP) : 0;
        st[t] = v0 + v1; __syncthreads();
        for (int s = 1; s < 256; s <<= 1) {
            int x = (t >= s) ? st[t - s] : 0;
            __syncthreads(); st[t] += x; __syncthreads();
        }
        int base = (t > 0) ? st[t - 1] : 0;
        if (2 * t < NBK)     B[2 * t] = base;
        if (2 * t + 1 < NBK) B[2 * t + 1] = base + v0;
        __syncthreads();
    }
}

// ---- fp32 GEMM-accumulate over 64x64 LDS tile (XOR-swizzled) — proj only ----
__device__ __forceinline__ void gemm_acc(const float4* X, const float4* __restrict__ wt4,
        int og, int ng, float4 acc[4])
{
    for (int k4 = 0; k4 < 16; ++k4) {
        float4 w0 = wt4[(4 * k4 + 0) * 16 + og];
        float4 w1 = wt4[(4 * k4 + 1) * 16 + og];
        float4 w2 = wt4[(4 * k4 + 2) * 16 + og];
        float4 w3 = wt4[(4 * k4 + 3) * 16 + og];
        #pragma unroll
        for (int j = 0; j < 4; ++j) {
            int n = ng * 4 + j;
            float4 xv = X[n * 16 + (k4 ^ ((n >> 2) & 7))];
            fma4(acc[j], xv.x, w0); fma4(acc[j], xv.y, w1);
            fma4(acc[j], xv.z, w2); fma4(acc[j], xv.w, w3);
        }
    }
}

// ---- proj bodies (16KB LDS); h output bf16 (unchanged) ----
__device__ __forceinline__ void proj_body128(const float* __restrict__ x,
        const float* __restrict__ wt, const float* __restrict__ bias,
        u16* __restrict__ hout, int i0, float4* smem)
{
    const int t = threadIdx.x;
    const int og = t & 15, ng = t >> 4;
    float4 acc[4];
    #pragma unroll
    for (int j = 0; j < 4; ++j) acc[j] = make_float4(0.f, 0.f, 0.f, 0.f);
    const float4* w4 = reinterpret_cast<const float4*>(wt);
    #pragma unroll
    for (int ph = 0; ph < 2; ++ph) {
        if (ph) __syncthreads();
        for (int idx = t; idx < 1024; idx += 256) {
            int n = idx >> 4, k4 = idx & 15;
            smem[n * 16 + (k4 ^ ((n >> 2) & 7))] =
                *reinterpret_cast<const float4*>(x + (size_t)(i0 + n) * 128 + ph * 64 + k4 * 4);
        }
        __syncthreads();
        gemm_acc(smem, w4 + ph * 1024, og, ng, acc);
    }
    float4 b = reinterpret_cast<const float4*>(bias)[og];
    #pragma unroll
    for (int j = 0; j < 4; ++j) {
        int node = i0 + ng * 4 + j;
        float4 o;
        o.x = fmaxf(acc[j].x + b.x, 0.f);
        o.y = fmaxf(acc[j].y + b.y, 0.f);
        o.z = fmaxf(acc[j].z + b.z, 0.f);
        o.w = fmaxf(acc[j].w + b.w, 0.f);
        *reinterpret_cast<ushort4*>(hout + (size_t)node * H + og * 4) = f2b4(o);
    }
}

__device__ __forceinline__ void proj_body64(const float* __restrict__ x,
        const float* __restrict__ wt, const float* __restrict__ bias,
        u16* __restrict__ hout, int i0, int nN, float4* smem)
{
    const int t = threadIdx.x;
    for (int idx = t; idx < 1024; idx += 256) {
        int n = idx >> 4, k4 = idx & 15;
        float4 v = make_float4(0.f, 0.f, 0.f, 0.f);
        if (i0 + n < nN)
            v = *reinterpret_cast<const float4*>(x + (size_t)(i0 + n) * 64 + k4 * 4);
        smem[n * 16 + (k4 ^ ((n >> 2) & 7))] = v;
    }
    __syncthreads();
    const int og = t & 15, ng = t >> 4;
    float4 acc[4];
    #pragma unroll
    for (int j = 0; j < 4; ++j) acc[j] = make_float4(0.f, 0.f, 0.f, 0.f);
    gemm_acc(smem, reinterpret_cast<const float4*>(wt), og, ng, acc);
    float4 b = reinterpret_cast<const float4*>(bias)[og];
    #pragma unroll
    for (int j = 0; j < 4; ++j) {
        int node = i0 + ng * 4 + j;
        if (node < nN) {
            float4 o;
            o.x = fmaxf(acc[j].x + b.x, 0.f);
            o.y = fmaxf(acc[j].y + b.y, 0.f);
            o.z = fmaxf(acc[j].z + b.z, 0.f);
            o.w = fmaxf(acc[j].w + b.w, 0.f);
            *reinterpret_cast<ushort4*>(hout + (size_t)node * H + og * 4) = f2b4(o);
        }
    }
}

// ==== K3: binB (per-bucket local CSR) + both projections (unchanged) ====
__global__ __launch_bounds__(256, 6) void binB_and_proj(
        const int* __restrict__ beC, const int* __restrict__ beU, const int* __restrict__ beA,
        const int* __restrict__ bktC, const int* __restrict__ bktU, const int* __restrict__ bktA,
        const int* __restrict__ bbC, const int* __restrict__ bbU, const int* __restrict__ bbA,
        int* __restrict__ rpC, int* __restrict__ rpU, int* __restrict__ rpA,
        int* __restrict__ colC, int* __restrict__ colU, int* __restrict__ colA,
        const float* __restrict__ xf, const float* __restrict__ wtf,
        const float* __restrict__ bf, u16* __restrict__ hf,
        const float* __restrict__ xa, const float* __restrict__ wta,
        const float* __restrict__ ba_, u16* __restrict__ ha)
{
    __shared__ __align__(16) int shraw[BCAP + 513 + 512];
    const int b = blockIdx.x, t = threadIdx.x;
    if (b < 3 * NBK) {
        int rel = b / NBK, bkt = b - rel * NBK;
        const int* be; const int* bc; const int* bbs; int* rp; int* col; int wlog, n;
        if (rel == 0)      { be = beC; bc = bktC; bbs = bbC; rp = rpC; col = colC; wlog = WLOG_F; n = N_FUNC; }
        else if (rel == 1) { be = beU; bc = bktU; bbs = bbU; rp = rpU; col = colU; wlog = WLOG_F; n = N_FUNC; }
        else               { be = beA; bc = bktA; bbs = bbA; rp = rpA; col = colA; wlog = WLOG_A; n = N_API; }
        const int width = 1 << wlog, mask = width - 1;
        const int nodeBase = bkt << wlog;
        const int nN = min(width, n - nodeBase);
        const int cnt = min(bc[bkt], BCAP);
        const int gb = bbs[bkt];
        int* colS = shraw;
        int* lrp  = shraw + BCAP;
        int* nxL  = shraw + BCAP + 513;
        for (int i = t; i <= 512; i += 256) { lrp[i] = 0; if (i < 512) nxL[i] = 0; }
        __syncthreads();
        const int* bePtr = be + (size_t)bkt * BCAP;
        for (int i = t; i < cnt; i += 256)
            atomicAdd(&lrp[bePtr[i] & mask], 1);
        __syncthreads();
        int v0 = lrp[2 * t], v1 = lrp[2 * t + 1];
        __syncthreads();
        int* st = colS;
        st[t] = v0 + v1; __syncthreads();
        for (int s = 1; s < 256; s <<= 1) {
            int x = (t >= s) ? st[t - s] : 0;
            __syncthreads(); st[t] += x; __syncthreads();
        }
        int base0 = (t > 0) ? st[t - 1] : 0;
        lrp[2 * t] = base0; lrp[2 * t + 1] = base0 + v0;
        if (t == 255) lrp[512] = st[255];
        __syncthreads();
        for (int i = t; i < nN; i += 256) rp[nodeBase + i] = gb + lrp[i];
        if (nodeBase + nN == n && t == 0) rp[n] = gb + lrp[nN];
        __syncthreads();
        for (int i = t; i < cnt; i += 256) {
            int en = bePtr[i]; int dl = en & mask;
            int pos = lrp[dl] + atomicAdd(&nxL[dl], 1);
            colS[pos] = en >> wlog;
        }
        __syncthreads();
        for (int i = t; i < cnt; i += 256) col[gb + i] = colS[i];
    } else {
        int b2 = b - 3 * NBK;
        float4* smem = reinterpret_cast<float4*>(shraw);
        if (b2 < NBF) proj_body128(xf, wtf, bf, hf, b2 * 64, smem);
        else          proj_body64(xa, wta, ba_, ha, (b2 - NBF) * 64, N_API, smem);
    }
}

// ---- async DMA: stage rows [c0,c1) of src (via col, or identity) ----
__device__ __forceinline__ void issue_rows(const u16* __restrict__ src_h,
        const int* __restrict__ col, int c0, int c1, u16* stage, int t)
{
    const int w = t >> 6, lane = t & 63;
    const int cnt = c1 - c0;
    for (int le0 = w * 8; le0 < cnt; le0 += 32) {
        int ge = c0 + min(le0 + (lane >> 3), cnt - 1);
        int srow = col ? col[ge] : ge;
        const u16* gp = src_h + (size_t)srow * H + (lane & 7) * 8;
        __builtin_amdgcn_global_load_lds(
            (const __attribute__((address_space(1))) u32*)gp,
            (__attribute__((address_space(3))) u32*)(stage + le0 * 64),
            16, 0, 0);
    }
}

__device__ __forceinline__ void consume_rows(const u16* stage, const int s4[4],
        const int e4[4], int c0, int c1, int L, float4 acc[4])
{
    #pragma unroll
    for (int p = 0; p < 4; ++p) {
        int jlo = max(s4[p], c0), jhi = min(e4[p], c1);
        for (int j = jlo; j < jhi; ++j) {
            ushort4 v = *reinterpret_cast<const ushort4*>(stage + (size_t)(j - c0) * 64 + L * 4);
            addb(acc[p], v);
        }
    }
}

// ---- MFMA GEMM, A from swizzled bf16 Xb tile ----
__device__ __forceinline__ void gemm_mfma_X(const u16* Xb, const u16* __restrict__ wpk,
        int wv, int lane, f32x4 acc[4])
{
    const int r = 16 * wv + (lane & 15);
    #pragma unroll
    for (int kt = 0; kt < 2; ++kt) {
        bf16x8 a = *reinterpret_cast<const bf16x8*>(
            Xb + r * 64 + (((kt * 4 + (lane >> 4)) ^ (r & 7)) << 3));
        #pragma unroll
        for (int nt = 0; nt < 4; ++nt) {
            bf16x8 bh = *reinterpret_cast<const bf16x8*>(wpk + ((kt * 256 + nt * 64 + lane) << 3));
            acc[nt] = __builtin_amdgcn_mfma_f32_16x16x32_bf16(a, bh, acc[nt], 0, 0, 0);
            bf16x8 bl = *reinterpret_cast<const bf16x8*>(wpk + 4096 + ((kt * 256 + nt * 64 + lane) << 3));
            acc[nt] = __builtin_amdgcn_mfma_f32_16x16x32_bf16(a, bl, acc[nt], 0, 0, 0);
        }
    }
}

// ---- MFMA GEMM, A from LINEAR bf16 stage rows ----
__device__ __forceinline__ void gemm_mfma_S(const u16* stage, const u16* __restrict__ wpk,
        int wv, int lane, f32x4 acc[4])
{
    const int r = 16 * wv + (lane & 15);
    #pragma unroll
    for (int kt = 0; kt < 2; ++kt) {
        bf16x8 a = *reinterpret_cast<const bf16x8*>(
            stage + r * 64 + kt * 32 + ((lane >> 4) << 3));
        #pragma unroll
        for (int nt = 0; nt < 4; ++nt) {
            bf16x8 bh = *reinterpret_cast<const bf16x8*>(wpk + ((kt * 256 + nt * 64 + lane) << 3));
            acc[nt] = __builtin_amdgcn_mfma_f32_16x16x32_bf16(a, bh, acc[nt], 0, 0, 0);
            bf16x8 bl = *reinterpret_cast<const bf16x8*>(wpk + 4096 + ((kt * 256 + nt * 64 + lane) << 3));
            acc[nt] = __builtin_amdgcn_mfma_f32_16x16x32_bf16(a, bl, acc[nt], 0, 0, 0);
        }
    }
}

// store fp32 aggregate (node n, dims 4L..4L+3) into swizzled bf16 Xb
__device__ __forceinline__ void store_agg(u16* Xb, int n, int L, float4 a)
{
    *reinterpret_cast<ushort4*>(Xb + n * 64 + (((L >> 1) ^ (n & 7)) << 3) + ((L & 1) << 2)) = f2b4(a);
}

// ---- fused layer: DMA-staged gather + MFMA GEMMs; fused mean-pool on last layer ----
__global__ __launch_bounds__(256, 5) void layer_both(
        const u16* __restrict__ hf_old, const u16* __restrict__ ha_old,
        u16* __restrict__ hf_new, u16* __restrict__ ha_new,
        const int* __restrict__ rpC, const int* __restrict__ colC,
        const int* __restrict__ rpU, const int* __restrict__ colU,
        const int* __restrict__ rpA, const int* __restrict__ colA,
        const u16* __restrict__ pk_r, const u16* __restrict__ pk_lc,
        const u16* __restrict__ pk_lu,
        const u16* __restrict__ pk_ruse, const u16* __restrict__ pk_luse,
        const float* __restrict__ bias_c, const float* __restrict__ bias_u,
        const float* __restrict__ bias_a,
        float* __restrict__ psh)
{
    __shared__ __align__(16) u16 Xb[64 * 64];       // 8 KB bf16 tile
    __shared__ __align__(16) u16 stage[SCAP * 64];  // 24 KB
    const int b = blockIdx.x;
    const int t = threadIdx.x;
    const int L = t & 15, g = t >> 4;
    const int wv = t >> 6, lane = t & 63;
    const float4 z4 = make_float4(0.f, 0.f, 0.f, 0.f);

    f32x4 acc[4];
    #pragma unroll
    for (int j = 0; j < 4; ++j) acc[j] = (f32x4){0.f, 0.f, 0.f, 0.f};

    if (b < NBF) {
        const int i0 = b * 64;
        int s1[4], e1[4];
        #pragma unroll
        for (int p = 0; p < 4; ++p) {
            int node = i0 + p * 16 + g;
            s1[p] = rpC[node]; e1[p] = rpC[node + 1];
        }
        const int be0 = rpC[i0], be1 = rpC[i0 + 64];
        // ---- P1: calls gather (chunked DMA) ----
        float4 a1[4];
        #pragma unroll
        for (int p = 0; p < 4; ++p) a1[p] = z4;
        for (int c0 = be0; c0 < be1; c0 += SCAP) {
            int c1 = min(c0 + SCAP, be1);
            issue_rows(hf_old, colC, c0, c1, stage, t);
            __syncthreads();
            consume_rows(stage, s1, e1, c0, c1, L, a1);
            __syncthreads();
        }
        #pragma unroll
        for (int p = 0; p < 4; ++p) {
            int n = p * 16 + g;
            scl4(a1[p], 1.0f / (float)max(e1[p] - s1[p], 1));
            store_agg(Xb, n, L, a1[p]);
        }
        __syncthreads();
        // ---- issue P2 chunk0; gemm1 (Wlc) hides flight ----
        int s2[4], e2[4];
        #pragma unroll
        for (int p = 0; p < 4; ++p) {
            int node = i0 + p * 16 + g;
            s2[p] = rpU[node]; e2[p] = rpU[node + 1];
        }
        const int ue0 = rpU[i0], ue1 = rpU[i0 + 64];
        int uc1 = min(ue0 + SCAP, ue1);
        if (ue1 > ue0) issue_rows(ha_old, colU, ue0, uc1, stage, t);
        gemm_mfma_X(Xb, pk_lc, wv, lane, acc);
        __syncthreads();
        // ---- P2 consume ----
        float4 a2[4];
        #pragma unroll
        for (int p = 0; p < 4; ++p) a2[p] = z4;
        if (ue1 > ue0) consume_rows(stage, s2, e2, ue0, uc1, L, a2);
        for (int c0 = uc1; c0 < ue1; c0 += SCAP) {
            int c1 = min(c0 + SCAP, ue1);
            __syncthreads();
            issue_rows(ha_old, colU, c0, c1, stage, t);
            __syncthreads();
            consume_rows(stage, s2, e2, c0, c1, L, a2);
        }
        __syncthreads();
        #pragma unroll
        for (int p = 0; p < 4; ++p) {
            int n = p * 16 + g;
            scl4(a2[p], 1.0f / (float)max(e2[p] - s2[p], 1));
            store_agg(Xb, n, L, a2[p]);
        }
        __syncthreads();
        // ---- issue P3 own rows; gemm2 (Wlu) hides flight ----
        issue_rows(hf_old, nullptr, i0, i0 + 64, stage, t);
        gemm_mfma_X(Xb, pk_lu, wv, lane, acc);
        __syncthreads();
        // ---- gemm3 (Wr) from linear stage ----
        gemm_mfma_S(stage, pk_r, wv, lane, acc);
        // ---- C -> Xb (linear), bias+relu, bf16 ----
        #pragma unroll
        for (int nt = 0; nt < 4; ++nt) {
            int col = nt * 16 + (lane & 15);
            float bvv = bias_c[col] + bias_u[col];
            #pragma unroll
            for (int rg = 0; rg < 4; ++rg) {
                int row = 16 * wv + (lane >> 4) * 4 + rg;
                Xb[row * 64 + col] = f2bf(fmaxf(acc[nt][rg] + bvv, 0.f));
            }
        }
        __syncthreads();
        // ---- write out + pool ----
        const int og = t & 15, ng = t >> 4;
        float4 s = z4;
        #pragma unroll
        for (int j = 0; j < 4; ++j) {
            int node = i0 + ng * 4 + j;
            ushort4 v = *reinterpret_cast<const ushort4*>(Xb + (ng * 4 + j) * 64 + og * 4);
            *reinterpret_cast<ushort4*>(hf_new + (size_t)node * H + og * 4) = v;
            if (psh) addb(s, v);
        }
        if (psh) {
            __syncthreads();
            float4* X4 = reinterpret_cast<float4*>(Xb);
            X4[ng * 16 + og] = s;
            __syncthreads();
            if (ng == 0) {
                float4 tot = z4;
                #pragma unroll
                for (int q = 0; q < 16; ++q) add4(tot, X4[q * 16 + og]);
                float* dst = psh + (size_t)(b & (NSHADOW - 1)) * 128 + og * 4;
                atomicAdd(dst + 0, tot.x); atomicAdd(dst + 1, tot.y);
                atomicAdd(dst + 2, tot.z); atomicAdd(dst + 3, tot.w);
            }
        }
    } else {
        const int i0 = (b - NBF) * 64;
        const int nTop = min(i0 + 64, N_API);
        int s1[4], e1[4];
        #pragma unroll
        for (int p = 0; p < 4; ++p) {
            int node = i0 + p * 16 + g;
            if (node < N_API) { s1[p] = rpA[node]; e1[p] = rpA[node + 1]; }
            else { s1[p] = 0; e1[p] = 0; }
        }
        const int be0 = rpA[i0], be1 = rpA[nTop];
        float4 a1[4];
        #pragma unroll
        for (int p = 0; p < 4; ++p) a1[p] = z4;
        for (int c0 = be0; c0 < be1; c0 += SCAP) {
            int c1 = min(c0 + SCAP, be1);
            issue_rows(hf_old, colA, c0, c1, stage, t);
            __syncthreads();
            consume_rows(stage, s1, e1, c0, c1, L, a1);
            __syncthreads();
        }
        #pragma unroll
        for (int p = 0; p < 4; ++p) {
            int n = p * 16 + g;
            scl4(a1[p], 1.0f / (float)max(e1[p] - s1[p], 1));
            store_agg(Xb, n, L, a1[p]);
        }
        __syncthreads();
        // ---- issue own rows; gemm1 (Wluse) hides ----
        issue_rows(ha_old, nullptr, i0, nTop, stage, t);
        gemm_mfma_X(Xb, pk_luse, wv, lane, acc);
        __syncthreads();
        gemm_mfma_S(stage, pk_ruse, wv, lane, acc);
        #pragma unroll
        for (int nt = 0; nt < 4; ++nt) {
            int col = nt * 16 + (lane & 15);
            float bvv = bias_a[col];
            #pragma unroll
            for (int rg = 0; rg < 4; ++rg) {
                int row = 16 * wv + (lane >> 4) * 4 + rg;
                Xb[row * 64 + col] = f2bf(fmaxf(acc[nt][rg] + bvv, 0.f));
            }
        }
        __syncthreads();
        const int og = t & 15, ng = t >> 4;
        float4 s = z4;
        #pragma unroll
        for (int j = 0; j < 4; ++j) {
            int node = i0 + ng * 4 + j;
            if (node < N_API) {
                ushort4 v = *reinterpret_cast<const ushort4*>(Xb + (ng * 4 + j) * 64 + og * 4);
                *reinterpret_cast<ushort4*>(ha_new + (size_t)node * H + og * 4) = v;
                if (psh) addb(s, v);
            }
        }
        if (psh) {
            __syncthreads();
            float4* X4 = reinterpret_cast<float4*>(Xb);
            X4[ng * 16 + og] = s;
            __syncthreads();
            if (ng == 0) {
                float4 tot = z4;
                #pragma unroll
                for (int q = 0; q < 16; ++q) add4(tot, X4[q * 16 + og]);
                float* dst = psh + (size_t)(b & (NSHADOW - 1)) * 128 + 64 + og * 4;
                atomicAdd(dst + 0, tot.x); atomicAdd(dst + 1, tot.y);
                atomicAdd(dst + 2, tot.z); atomicAdd(dst + 3, tot.w);
            }
        }
    }
}

__global__ __launch_bounds__(128) void classifier_kernel(const float* __restrict__ shadows,
        const float* __restrict__ Wc1, const float* __restrict__ bc1,
        const float* __restrict__ Wc2, const float* __restrict__ bc2,
        float* __restrict__ out)
{
    __shared__ float ps[128];
    __shared__ float z1[64];
    int t = threadIdx.x;
    float s = 0.f;
    for (int q = 0; q < NSHADOW; ++q) s += shadows[q * 128 + t];
    ps[t] = s * (t < 64 ? (1.0f / N_FUNC) : (1.0f / N_API));
    __syncthreads();
    if (t < 64) {
        float a = bc1[t];
        for (int k = 0; k < 128; ++k) a = fmaf(ps[k], Wc1[t * 128 + k], a);
        z1[t] = fmaxf(a, 0.f);
    }
    __syncthreads();
    if (t < 2) {
        float a = bc2[t];
        for (int j = 0; j < 64; ++j) a = fmaf(z1[j], Wc2[t * 64 + j], a);
        out[t] = a;
    }
}

extern "C" void kernel_launch(void* const* d_in, const int* in_sizes, int n_in,
                              void* d_out, int out_size, void* d_ws, size_t ws_size,
                              hipStream_t stream)
{
    const float* x_func    = (const float*)d_in[0];
    const float* x_api     = (const float*)d_in[1];
    const float* w_in_func = (const float*)d_in[2];
    const float* b_in_func = (const float*)d_in[3];
    const float* w_in_api  = (const float*)d_in[4];
    const float* b_in_api  = (const float*)d_in[5];
    const float* Wl_calls  = (const float*)d_in[6];
    const float* bl_calls  = (const float*)d_in[7];
    const float* Wr_calls  = (const float*)d_in[8];
    const float* Wl_uses   = (const float*)d_in[9];
    const float* bl_uses   = (const float*)d_in[10];
    const float* Wr_uses   = (const float*)d_in[11];
    const float* Wl_usedby = (const float*)d_in[12];
    const float* bl_usedby = (const float*)d_in[13];
    const float* Wr_usedby = (const float*)d_in[14];
    const float* Wc1       = (const float*)d_in[15];
    const float* bc1       = (const float*)d_in[16];
    const float* Wc2       = (const float*)d_in[17];
    const float* bc2       = (const float*)d_in[18];
    const int*   ei_calls  = (const int*)d_in[19];
    const int*   ei_uses   = (const int*)d_in[20];
    const int*   ei_usedby = (const int*)d_in[21];
    const int E = in_sizes[19] / 2;

    float* ws = (float*)d_ws;
    size_t off = 0;
    u16* hf0 = (u16*)(ws + off); off += (size_t)N_FUNC * 32;
    u16* hf1 = (u16*)(ws + off); off += (size_t)N_FUNC * 32;
    u16* ha0 = (u16*)(ws + off); off += (size_t)N_API * 32;
    u16* ha1 = (u16*)(ws + off); off += (size_t)N_API * 32;
    float* prep = ws + off; off += 12288;            // proj weights fp32
    u16* wpk = (u16*)(ws + off); off += 40960;       // 10 x 8192 u16 packed
    int* bktC = (int*)(ws + off); off += NBK;
    int* bktU = (int*)(ws + off); off += NBK;
    int* bktA = (int*)(ws + off); off += NBK;
    float* shadows = ws + off; off += NSHADOW * 128;
    int* bbC = (int*)(ws + off); off += NBK;
    int* bbU = (int*)(ws + off); off += NBK;
    int* bbA = (int*)(ws + off); off += NBK;
    int* rpC = (int*)(ws + off); off += N_FUNC + 1;
    int* rpU = (int*)(ws + off); off += N_FUNC + 1;
    int* rpA = (int*)(ws + off); off += N_API + 1;
    int* colC = (int*)(ws + off); off += E;
    int* colU = (int*)(ws + off); off += E;
    int* colA = (int*)(ws + off); off += E;
    int* beC = (int*)(ws + off); off += (size_t)NBK * BCAP;
    int* beU = (int*)(ws + off); off += (size_t)NBK * BCAP;
    int* beA = (int*)(ws + off); off += (size_t)NBK * BCAP;

    const int nbPerRel = (E + EPB - 1) / EPB;

    hipMemsetAsync(bktC, 0, (size_t)(3 * NBK + NSHADOW * 128) * sizeof(float), stream);

    prep_and_binA<<<PREPB + 3 * nbPerRel, 256, 0, stream>>>(
            w_in_func, w_in_api, Wl_calls, Wr_calls, Wl_uses, Wr_uses,
            Wl_usedby, Wr_usedby, prep, wpk,
            ei_calls, ei_calls + E, ei_usedby, ei_usedby + E, ei_uses, ei_uses + E,
            bktC, bktU, bktA, beC, beU, beA, E, nbPerRel);

    scan_buckets<<<1, 256, 0, stream>>>(bktC, bktU, bktA, bbC, bbU, bbA);

    float* wt_in_func = prep;
    float* wt_in_api  = prep + 8192;
    u16 *pk_r[NLAYERS], *pk_lc[NLAYERS], *pk_lu[NLAYERS], *pk_luse[NLAYERS], *pk_ruse[NLAYERS];
    for (int l = 0; l < NLAYERS; ++l) {
        pk_r[l]    = wpk + (size_t)(l * 5 + 0) * 8192;
        pk_lc[l]   = wpk + (size_t)(l * 5 + 1) * 8192;
        pk_lu[l]   = wpk + (size_t)(l * 5 + 2) * 8192;
        pk_luse[l] = wpk + (size_t)(l * 5 + 3) * 8192;
        pk_ruse[l] = wpk + (size_t)(l * 5 + 4) * 8192;
    }

    binB_and_proj<<<3 * NBK + NBF + NBA, 256, 0, stream>>>(
            beC, beU, beA, bktC, bktU, bktA, bbC, bbU, bbA,
            rpC, rpU, rpA, colC, colU, colA,
            x_func, wt_in_func, b_in_func, hf0,
            x_api, wt_in_api, b_in_api, ha0);

    u16* hf[2] = { hf0, hf1 };
    u16* ha[2] = { ha0, ha1 };
    for (int l = 0; l < NLAYERS; ++l) {
        int cur = l & 1, nxt = cur ^ 1;
        layer_both<<<NBF + NBA, 256, 0, stream>>>(
                hf[cur], ha[cur], hf[nxt], ha[nxt],
                rpC, colC, rpU, colU, rpA, colA,
                pk_r[l], pk_lc[l], pk_lu[l], pk_ruse[l], pk_luse[l],
                bl_calls + l * 64, bl_usedby + l * 64, bl_uses + l * 64,
                (l == NLAYERS - 1) ? shadows : nullptr);
    }

    classifier_kernel<<<1, 128, 0, stream>>>(shadows, Wc1, bc1, Wc2, bc2, (float*)d_out);
}

// Round 14
// 210.677 us; speedup vs baseline: 2.6728x; 1.1574x over previous
//
#include <hip/hip_runtime.h>

#define N_FUNC 200000
#define N_API  50000
#define H      64
#define NLAYERS 2
#define NBF 3125   // N_FUNC/64 exact
#define NBA 782    // ceil(N_API/64)
#define PREPB 416  // ceil(106496/256) packed-weight prep blocks
#define NSHADOW 64
#define NBK   391  // buckets per relation
#define BCAP  4096
#define EPB   4096
#define WLOG_F 9
#define WLOG_A 7
#define SCAP  192  // staged edge rows per chunk (24KB)

typedef unsigned short u16;
typedef unsigned int u32;
typedef __bf16 bf16x8 __attribute__((ext_vector_type(8)));
typedef float f32x4 __attribute__((ext_vector_type(4)));
typedef unsigned short u16x8 __attribute__((ext_vector_type(8)));

__device__ __forceinline__ void add4(float4& a, float4 v) {
    a.x += v.x; a.y += v.y; a.z += v.z; a.w += v.w;
}
__device__ __forceinline__ void scl4(float4& a, float s) {
    a.x *= s; a.y *= s; a.z *= s; a.w *= s;
}
__device__ __forceinline__ float bf2f(u16 u) {
    return __uint_as_float(((unsigned int)u) << 16);
}
__device__ __forceinline__ u16 f2bf(float f) {   // RNE
    unsigned int x = __float_as_uint(f);
    return (u16)((x + 0x7FFFu + ((x >> 16) & 1u)) >> 16);
}
__device__ __forceinline__ float4 b2f4(ushort4 v) {
    return make_float4(bf2f(v.x), bf2f(v.y), bf2f(v.z), bf2f(v.w));
}
__device__ __forceinline__ ushort4 f2b4(float4 o) {
    ushort4 r; r.x = f2bf(o.x); r.y = f2bf(o.y); r.z = f2bf(o.z); r.w = f2bf(o.w);
    return r;
}
__device__ __forceinline__ void addb(float4& a, ushort4 v) {
    a.x += bf2f(v.x); a.y += bf2f(v.y); a.z += bf2f(v.z); a.w += bf2f(v.w);
}

// ==== K1: packed hi/lo bf16 weight prep (proj + layers) + binA bucket-scatter ====
// wpk u16 idx space:
//  [0,16384):  proj func  (K=128): half=idx>>13, w=idx&8191
//  [16384,24576): proj api (K=64): r=idx-16384, half=r>>12, w=r&4095
//  [24576,106496): 10 layer matrices: r=idx-24576, m=r>>13, half=(r>>12)&1, w=r&4095
__global__ __launch_bounds__(256, 6) void prep_and_binA(
        const float* __restrict__ w_in_func, const float* __restrict__ w_in_api,
        const float* __restrict__ Wl_calls, const float* __restrict__ Wr_calls,
        const float* __restrict__ Wl_uses,  const float* __restrict__ Wr_uses,
        const float* __restrict__ Wl_usedby,const float* __restrict__ Wr_usedby,
        u16* __restrict__ wpk,
        const int* __restrict__ sC, const int* __restrict__ dC,
        const int* __restrict__ sU, const int* __restrict__ dU,
        const int* __restrict__ sA, const int* __restrict__ dA,
        int* __restrict__ bktC, int* __restrict__ bktU, int* __restrict__ bktA,
        int* __restrict__ beC, int* __restrict__ beU, int* __restrict__ beA,
        int E, int nbPerRel)
{
    __shared__ int staged[EPB];
    __shared__ int hist[NBK + 1];
    __shared__ int lcnt[NBK];
    __shared__ int gbase[NBK];
    __shared__ int stemp[256];
    const int b = blockIdx.x, t = threadIdx.x;
    if (b < PREPB) {
        int idx = b * 256 + t;
        if (idx < 106496) {
            int half, w, K;
            const float* A; const float* B = nullptr;
            if (idx < 16384) {
                half = idx >> 13; w = idx & 8191; K = 128; A = w_in_func;
            } else if (idx < 24576) {
                int r = idx - 16384;
                half = r >> 12; w = r & 4095; K = 64; A = w_in_api;
            } else {
                int r = idx - 24576;
                int m = r >> 13;
                half = (r >> 12) & 1; w = r & 4095; K = 64;
                int l = m / 5, which = m - 5 * l;
                if (which == 0)      { A = Wr_calls  + l * 4096; B = Wr_usedby + l * 4096; }
                else if (which == 1)   A = Wl_calls  + l * 4096;
                else if (which == 2)   A = Wl_usedby + l * 4096;
                else if (which == 3)   A = Wl_uses   + l * 4096;
                else                   A = Wr_uses   + l * 4096;
            }
            int kt = w >> 11;
            int nt = (w >> 9) & 3;
            int lane = (w >> 3) & 63;
            int i = w & 7;
            int k = kt * 32 + (lane >> 4) * 8 + i;
            int n = nt * 16 + (lane & 15);
            float v = A[n * K + k];
            if (B) v += B[n * K + k];
            u16 hi = f2bf(v);
            wpk[idx] = half ? f2bf(v - bf2f(hi)) : hi;
        }
        return;
    }
    int bb = b - PREPB;
    int rel = bb / nbPerRel, lb = bb - rel * nbPerRel;
    const int* srcA; const int* dstA; int* bcnt; int* be; int wlog;
    if (rel == 0)      { srcA = sC; dstA = dC; bcnt = bktC; be = beC; wlog = WLOG_F; }
    else if (rel == 1) { srcA = sU; dstA = dU; bcnt = bktU; be = beU; wlog = WLOG_F; }
    else               { srcA = sA; dstA = dA; bcnt = bktA; be = beA; wlog = WLOG_A; }
    const int mask = (1 << wlog) - 1;
    const int e0 = lb * EPB;
    const int cnt = min(EPB, E - e0);
    for (int i = t; i < NBK; i += 256) { hist[i] = 0; lcnt[i] = 0; }
    __syncthreads();
    for (int i = t; i < cnt; i += 256)
        atomicAdd(&hist[dstA[e0 + i] >> wlog], 1);
    __syncthreads();
    int v0 = (2 * t < NBK) ? hist[2 * t] : 0;
    int v1 = (2 * t + 1 < NBK) ? hist[2 * t + 1] : 0;
    __syncthreads();
    stemp[t] = v0 + v1; __syncthreads();
    for (int s = 1; s < 256; s <<= 1) {
        int x = (t >= s) ? stemp[t - s] : 0;
        __syncthreads(); stemp[t] += x; __syncthreads();
    }
    int base = (t > 0) ? stemp[t - 1] : 0;
    if (2 * t < NBK)     hist[2 * t] = base;
    if (2 * t + 1 < NBK) hist[2 * t + 1] = base + v0;
    if (t == 255) hist[NBK] = stemp[255];
    __syncthreads();
    for (int i = t; i < cnt; i += 256) {
        int d = dstA[e0 + i], s = srcA[e0 + i];
        int bin = d >> wlog;
        int loc = atomicAdd(&lcnt[bin], 1);
        staged[hist[bin] + loc] = (s << wlog) | (d & mask);
    }
    __syncthreads();
    for (int i = t; i < NBK; i += 256) {
        int c = hist[i + 1] - hist[i];
        gbase[i] = (c > 0) ? atomicAdd(&bcnt[i], c) : 0;
    }
    __syncthreads();
    int wv = t >> 6, ln = t & 63;
    for (int bin = wv; bin < NBK; bin += 4) {
        int l0 = hist[bin], c = hist[bin + 1] - l0;
        int gb = gbase[bin];
        for (int k = ln; k < c; k += 64)
            if (gb + k < BCAP)
                be[(size_t)bin * BCAP + gb + k] = staged[l0 + k];
    }
}

// ==== K2: exclusive scan of 3x391 bucket counts ====
__global__ __launch_bounds__(256) void scan_buckets(
        const int* __restrict__ bktC, const int* __restrict__ bktU, const int* __restrict__ bktA,
        int* __restrict__ bbC, int* __restrict__ bbU, int* __restrict__ bbA)
{
    __shared__ int st[256];
    int t = threadIdx.x;
    for (int r = 0; r < 3; ++r) {
        const int* c = (r == 0) ? bktC : (r == 1) ? bktU : bktA;
        int* B = (r == 0) ? bbC : (r == 1) ? bbU : bbA;
        int v0 = (2 * t < NBK) ? min(c[2 * t], BCAP) : 0;
        int v1 = (2 * t + 1 < NBK) ? min(c[2 * t + 1], BCAP) : 0;
        st[t] = v0 + v1; __syncthreads();
        for (int s = 1; s < 256; s <<= 1) {
            int x = (t >= s) ? st[t - s] : 0;
            __syncthreads(); st[t] += x; __syncthreads();
        }
        int base = (t > 0) ? st[t - 1] : 0;
        if (2 * t < NBK)     B[2 * t] = base;
        if (2 * t + 1 < NBK) B[2 * t + 1] = base + v0;
        __syncthreads();
    }
}

// ---- MFMA proj: x (fp32, hi/lo split in-register) @ W (packed hi/lo bf16) ----
template<int K>
__device__ __forceinline__ void proj_mfma(const float* __restrict__ x,
        const u16* __restrict__ wpk, const float* __restrict__ bias,
        u16* __restrict__ hout, int i0, int nN, u16* Xb)
{
    const int t = threadIdx.x;
    const int wv = t >> 6, lane = t & 63;
    const int row = 16 * wv + (lane & 15);
    const int node = i0 + row;
    constexpr int halfOff = K * 64;
    f32x4 acc[4];
    #pragma unroll
    for (int j = 0; j < 4; ++j) acc[j] = (f32x4){0.f, 0.f, 0.f, 0.f};
    #pragma unroll
    for (int kt = 0; kt < K / 32; ++kt) {
        float v[8];
        if (node < nN) {
            const float* xp = x + (size_t)node * K + kt * 32 + (lane >> 4) * 8;
            #pragma unroll
            for (int i = 0; i < 8; ++i) v[i] = xp[i];
        } else {
            #pragma unroll
            for (int i = 0; i < 8; ++i) v[i] = 0.f;
        }
        u16x8 hh, ll;
        #pragma unroll
        for (int i = 0; i < 8; ++i) {
            u16 h = f2bf(v[i]);
            hh[i] = h;
            ll[i] = f2bf(v[i] - bf2f(h));
        }
        bf16x8 ah = __builtin_bit_cast(bf16x8, hh);
        bf16x8 al = __builtin_bit_cast(bf16x8, ll);
        #pragma unroll
        for (int nt = 0; nt < 4; ++nt) {
            bf16x8 bh = *reinterpret_cast<const bf16x8*>(wpk + (((kt * 4 + nt) * 64 + lane) << 3));
            bf16x8 bl = *reinterpret_cast<const bf16x8*>(wpk + halfOff + (((kt * 4 + nt) * 64 + lane) << 3));
            acc[nt] = __builtin_amdgcn_mfma_f32_16x16x32_bf16(ah, bh, acc[nt], 0, 0, 0);
            acc[nt] = __builtin_amdgcn_mfma_f32_16x16x32_bf16(al, bh, acc[nt], 0, 0, 0);
            acc[nt] = __builtin_amdgcn_mfma_f32_16x16x32_bf16(ah, bl, acc[nt], 0, 0, 0);
        }
    }
    // C -> Xb (linear u16), bias+relu
    #pragma unroll
    for (int nt = 0; nt < 4; ++nt) {
        int col = nt * 16 + (lane & 15);
        float bvv = bias[col];
        #pragma unroll
        for (int rg = 0; rg < 4; ++rg) {
            int r = 16 * wv + (lane >> 4) * 4 + rg;
            Xb[r * 64 + col] = f2bf(fmaxf(acc[nt][rg] + bvv, 0.f));
        }
    }
    __syncthreads();
    const int og = t & 15, ng = t >> 4;
    #pragma unroll
    for (int j = 0; j < 4; ++j) {
        int node2 = i0 + ng * 4 + j;
        if (node2 < nN) {
            ushort4 v = *reinterpret_cast<const ushort4*>(Xb + (ng * 4 + j) * 64 + og * 4);
            *reinterpret_cast<ushort4*>(hout + (size_t)node2 * H + og * 4) = v;
        }
    }
}

// ==== K3: binB (per-bucket local CSR) + both projections (MFMA) ====
__global__ __launch_bounds__(256, 6) void binB_and_proj(
        const int* __restrict__ beC, const int* __restrict__ beU, const int* __restrict__ beA,
        const int* __restrict__ bktC, const int* __restrict__ bktU, const int* __restrict__ bktA,
        const int* __restrict__ bbC, const int* __restrict__ bbU, const int* __restrict__ bbA,
        int* __restrict__ rpC, int* __restrict__ rpU, int* __restrict__ rpA,
        int* __restrict__ colC, int* __restrict__ colU, int* __restrict__ colA,
        const float* __restrict__ xf, const u16* __restrict__ wpkf,
        const float* __restrict__ bf, u16* __restrict__ hf,
        const float* __restrict__ xa, const u16* __restrict__ wpka,
        const float* __restrict__ ba_, u16* __restrict__ ha)
{
    __shared__ __align__(16) int shraw[BCAP + 513 + 512];
    const int b = blockIdx.x, t = threadIdx.x;
    if (b < 3 * NBK) {
        int rel = b / NBK, bkt = b - rel * NBK;
        const int* be; const int* bc; const int* bbs; int* rp; int* col; int wlog, n;
        if (rel == 0)      { be = beC; bc = bktC; bbs = bbC; rp = rpC; col = colC; wlog = WLOG_F; n = N_FUNC; }
        else if (rel == 1) { be = beU; bc = bktU; bbs = bbU; rp = rpU; col = colU; wlog = WLOG_F; n = N_FUNC; }
        else               { be = beA; bc = bktA; bbs = bbA; rp = rpA; col = colA; wlog = WLOG_A; n = N_API; }
        const int width = 1 << wlog, mask = width - 1;
        const int nodeBase = bkt << wlog;
        const int nN = min(width, n - nodeBase);
        const int cnt = min(bc[bkt], BCAP);
        const int gb = bbs[bkt];
        int* colS = shraw;
        int* lrp  = shraw + BCAP;
        int* nxL  = shraw + BCAP + 513;
        for (int i = t; i <= 512; i += 256) { lrp[i] = 0; if (i < 512) nxL[i] = 0; }
        __syncthreads();
        const int* bePtr = be + (size_t)bkt * BCAP;
        for (int i = t; i < cnt; i += 256)
            atomicAdd(&lrp[bePtr[i] & mask], 1);
        __syncthreads();
        int v0 = lrp[2 * t], v1 = lrp[2 * t + 1];
        __syncthreads();
        int* st = colS;
        st[t] = v0 + v1; __syncthreads();
        for (int s = 1; s < 256; s <<= 1) {
            int x = (t >= s) ? st[t - s] : 0;
            __syncthreads(); st[t] += x; __syncthreads();
        }
        int base0 = (t > 0) ? st[t - 1] : 0;
        lrp[2 * t] = base0; lrp[2 * t + 1] = base0 + v0;
        if (t == 255) lrp[512] = st[255];
        __syncthreads();
        for (int i = t; i < nN; i += 256) rp[nodeBase + i] = gb + lrp[i];
        if (nodeBase + nN == n && t == 0) rp[n] = gb + lrp[nN];
        __syncthreads();
        for (int i = t; i < cnt; i += 256) {
            int en = bePtr[i]; int dl = en & mask;
            int pos = lrp[dl] + atomicAdd(&nxL[dl], 1);
            colS[pos] = en >> wlog;
        }
        __syncthreads();
        for (int i = t; i < cnt; i += 256) col[gb + i] = colS[i];
    } else {
        int b2 = b - 3 * NBK;
        u16* Xb = reinterpret_cast<u16*>(shraw);
        if (b2 < NBF) proj_mfma<128>(xf, wpkf, bf, hf, b2 * 64, N_FUNC, Xb);
        else          proj_mfma<64>(xa, wpka, ba_, ha, (b2 - NBF) * 64, N_API, Xb);
    }
}

// ---- async DMA: stage rows [c0,c1) of src (via col, or identity) ----
__device__ __forceinline__ void issue_rows(const u16* __restrict__ src_h,
        const int* __restrict__ col, int c0, int c1, u16* stage, int t)
{
    const int w = t >> 6, lane = t & 63;
    const int cnt = c1 - c0;
    for (int le0 = w * 8; le0 < cnt; le0 += 32) {
        int ge = c0 + min(le0 + (lane >> 3), cnt - 1);
        int srow = col ? col[ge] : ge;
        const u16* gp = src_h + (size_t)srow * H + (lane & 7) * 8;
        __builtin_amdgcn_global_load_lds(
            (const __attribute__((address_space(1))) u32*)gp,
            (__attribute__((address_space(3))) u32*)(stage + le0 * 64),
            16, 0, 0);
    }
}

__device__ __forceinline__ void consume_rows(const u16* stage, const int s4[4],
        const int e4[4], int c0, int c1, int L, float4 acc[4])
{
    #pragma unroll
    for (int p = 0; p < 4; ++p) {
        int jlo = max(s4[p], c0), jhi = min(e4[p], c1);
        for (int j = jlo; j < jhi; ++j) {
            ushort4 v = *reinterpret_cast<const ushort4*>(stage + (size_t)(j - c0) * 64 + L * 4);
            addb(acc[p], v);
        }
    }
}

// ---- MFMA GEMM, A from swizzled bf16 Xb tile ----
__device__ __forceinline__ void gemm_mfma_X(const u16* Xb, const u16* __restrict__ wpk,
        int wv, int lane, f32x4 acc[4])
{
    const int r = 16 * wv + (lane & 15);
    #pragma unroll
    for (int kt = 0; kt < 2; ++kt) {
        bf16x8 a = *reinterpret_cast<const bf16x8*>(
            Xb + r * 64 + (((kt * 4 + (lane >> 4)) ^ (r & 7)) << 3));
        #pragma unroll
        for (int nt = 0; nt < 4; ++nt) {
            bf16x8 bh = *reinterpret_cast<const bf16x8*>(wpk + ((kt * 256 + nt * 64 + lane) << 3));
            acc[nt] = __builtin_amdgcn_mfma_f32_16x16x32_bf16(a, bh, acc[nt], 0, 0, 0);
            bf16x8 bl = *reinterpret_cast<const bf16x8*>(wpk + 4096 + ((kt * 256 + nt * 64 + lane) << 3));
            acc[nt] = __builtin_amdgcn_mfma_f32_16x16x32_bf16(a, bl, acc[nt], 0, 0, 0);
        }
    }
}

// ---- MFMA GEMM, A from LINEAR bf16 stage rows ----
__device__ __forceinline__ void gemm_mfma_S(const u16* stage, const u16* __restrict__ wpk,
        int wv, int lane, f32x4 acc[4])
{
    const int r = 16 * wv + (lane & 15);
    #pragma unroll
    for (int kt = 0; kt < 2; ++kt) {
        bf16x8 a = *reinterpret_cast<const bf16x8*>(
            stage + r * 64 + kt * 32 + ((lane >> 4) << 3));
        #pragma unroll
        for (int nt = 0; nt < 4; ++nt) {
            bf16x8 bh = *reinterpret_cast<const bf16x8*>(wpk + ((kt * 256 + nt * 64 + lane) << 3));
            acc[nt] = __builtin_amdgcn_mfma_f32_16x16x32_bf16(a, bh, acc[nt], 0, 0, 0);
            bf16x8 bl = *reinterpret_cast<const bf16x8*>(wpk + 4096 + ((kt * 256 + nt * 64 + lane) << 3));
            acc[nt] = __builtin_amdgcn_mfma_f32_16x16x32_bf16(a, bl, acc[nt], 0, 0, 0);
        }
    }
}

__device__ __forceinline__ void store_agg(u16* Xb, int n, int L, float4 a)
{
    *reinterpret_cast<ushort4*>(Xb + n * 64 + (((L >> 1) ^ (n & 7)) << 3) + ((L & 1) << 2)) = f2b4(a);
}

// ---- fused layer: DMA-staged gather + MFMA GEMMs; fused mean-pool on last layer ----
__global__ __launch_bounds__(256, 5) void layer_both(
        const u16* __restrict__ hf_old, const u16* __restrict__ ha_old,
        u16* __restrict__ hf_new, u16* __restrict__ ha_new,
        const int* __restrict__ rpC, const int* __restrict__ colC,
        const int* __restrict__ rpU, const int* __restrict__ colU,
        const int* __restrict__ rpA, const int* __restrict__ colA,
        const u16* __restrict__ pk_r, const u16* __restrict__ pk_lc,
        const u16* __restrict__ pk_lu,
        const u16* __restrict__ pk_ruse, const u16* __restrict__ pk_luse,
        const float* __restrict__ bias_c, const float* __restrict__ bias_u,
        const float* __restrict__ bias_a,
        float* __restrict__ psh)
{
    __shared__ __align__(16) u16 Xb[64 * 64];       // 8 KB bf16 tile
    __shared__ __align__(16) u16 stage[SCAP * 64];  // 24 KB
    const int b = blockIdx.x;
    const int t = threadIdx.x;
    const int L = t & 15, g = t >> 4;
    const int wv = t >> 6, lane = t & 63;
    const float4 z4 = make_float4(0.f, 0.f, 0.f, 0.f);

    f32x4 acc[4];
    #pragma unroll
    for (int j = 0; j < 4; ++j) acc[j] = (f32x4){0.f, 0.f, 0.f, 0.f};

    if (b < NBF) {
        const int i0 = b * 64;
        int s1[4], e1[4];
        #pragma unroll
        for (int p = 0; p < 4; ++p) {
            int node = i0 + p * 16 + g;
            s1[p] = rpC[node]; e1[p] = rpC[node + 1];
        }
        const int be0 = rpC[i0], be1 = rpC[i0 + 64];
        float4 a1[4];
        #pragma unroll
        for (int p = 0; p < 4; ++p) a1[p] = z4;
        for (int c0 = be0; c0 < be1; c0 += SCAP) {
            int c1 = min(c0 + SCAP, be1);
            issue_rows(hf_old, colC, c0, c1, stage, t);
            __syncthreads();
            consume_rows(stage, s1, e1, c0, c1, L, a1);
            __syncthreads();
        }
        #pragma unroll
        for (int p = 0; p < 4; ++p) {
            int n = p * 16 + g;
            scl4(a1[p], 1.0f / (float)max(e1[p] - s1[p], 1));
            store_agg(Xb, n, L, a1[p]);
        }
        __syncthreads();
        int s2[4], e2[4];
        #pragma unroll
        for (int p = 0; p < 4; ++p) {
            int node = i0 + p * 16 + g;
            s2[p] = rpU[node]; e2[p] = rpU[node + 1];
        }
        const int ue0 = rpU[i0], ue1 = rpU[i0 + 64];
        int uc1 = min(ue0 + SCAP, ue1);
        if (ue1 > ue0) issue_rows(ha_old, colU, ue0, uc1, stage, t);
        gemm_mfma_X(Xb, pk_lc, wv, lane, acc);
        __syncthreads();
        float4 a2[4];
        #pragma unroll
        for (int p = 0; p < 4; ++p) a2[p] = z4;
        if (ue1 > ue0) consume_rows(stage, s2, e2, ue0, uc1, L, a2);
        for (int c0 = uc1; c0 < ue1; c0 += SCAP) {
            int c1 = min(c0 + SCAP, ue1);
            __syncthreads();
            issue_rows(ha_old, colU, c0, c1, stage, t);
            __syncthreads();
            consume_rows(stage, s2, e2, c0, c1, L, a2);
        }
        __syncthreads();
        #pragma unroll
        for (int p = 0; p < 4; ++p) {
            int n = p * 16 + g;
            scl4(a2[p], 1.0f / (float)max(e2[p] - s2[p], 1));
            store_agg(Xb, n, L, a2[p]);
        }
        __syncthreads();
        issue_rows(hf_old, nullptr, i0, i0 + 64, stage, t);
        gemm_mfma_X(Xb, pk_lu, wv, lane, acc);
        __syncthreads();
        gemm_mfma_S(stage, pk_r, wv, lane, acc);
        #pragma unroll
        for (int nt = 0; nt < 4; ++nt) {
            int col = nt * 16 + (lane & 15);
            float bvv = bias_c[col] + bias_u[col];
            #pragma unroll
            for (int rg = 0; rg < 4; ++rg) {
                int row = 16 * wv + (lane >> 4) * 4 + rg;
                Xb[row * 64 + col] = f2bf(fmaxf(acc[nt][rg] + bvv, 0.f));
            }
        }
        __syncthreads();
        const int og = t & 15, ng = t >> 4;
        float4 s = z4;
        #pragma unroll
        for (int j = 0; j < 4; ++j) {
            int node = i0 + ng * 4 + j;
            ushort4 v = *reinterpret_cast<const ushort4*>(Xb + (ng * 4 + j) * 64 + og * 4);
            *reinterpret_cast<ushort4*>(hf_new + (size_t)node * H + og * 4) = v;
            if (psh) addb(s, v);
        }
        if (psh) {
            __syncthreads();
            float4* X4 = reinterpret_cast<float4*>(Xb);
            X4[ng * 16 + og] = s;
            __syncthreads();
            if (ng == 0) {
                float4 tot = z4;
                #pragma unroll
                for (int q = 0; q < 16; ++q) add4(tot, X4[q * 16 + og]);
                float* dst = psh + (size_t)(b & (NSHADOW - 1)) * 128 + og * 4;
                atomicAdd(dst + 0, tot.x); atomicAdd(dst + 1, tot.y);
                atomicAdd(dst + 2, tot.z); atomicAdd(dst + 3, tot.w);
            }
        }
    } else {
        const int i0 = (b - NBF) * 64;
        const int nTop = min(i0 + 64, N_API);
        int s1[4], e1[4];
        #pragma unroll
        for (int p = 0; p < 4; ++p) {
            int node = i0 + p * 16 + g;
            if (node < N_API) { s1[p] = rpA[node]; e1[p] = rpA[node + 1]; }
            else { s1[p] = 0; e1[p] = 0; }
        }
        const int be0 = rpA[i0], be1 = rpA[nTop];
        float4 a1[4];
        #pragma unroll
        for (int p = 0; p < 4; ++p) a1[p] = z4;
        for (int c0 = be0; c0 < be1; c0 += SCAP) {
            int c1 = min(c0 + SCAP, be1);
            issue_rows(hf_old, colA, c0, c1, stage, t);
            __syncthreads();
            consume_rows(stage, s1, e1, c0, c1, L, a1);
            __syncthreads();
        }
        #pragma unroll
        for (int p = 0; p < 4; ++p) {
            int n = p * 16 + g;
            scl4(a1[p], 1.0f / (float)max(e1[p] - s1[p], 1));
            store_agg(Xb, n, L, a1[p]);
        }
        __syncthreads();
        issue_rows(ha_old, nullptr, i0, nTop, stage, t);
        gemm_mfma_X(Xb, pk_luse, wv, lane, acc);
        __syncthreads();
        gemm_mfma_S(stage, pk_ruse, wv, lane, acc);
        #pragma unroll
        for (int nt = 0; nt < 4; ++nt) {
            int col = nt * 16 + (lane & 15);
            float bvv = bias_a[col];
            #pragma unroll
            for (int rg = 0; rg < 4; ++rg) {
                int row = 16 * wv + (lane >> 4) * 4 + rg;
                Xb[row * 64 + col] = f2bf(fmaxf(acc[nt][rg] + bvv, 0.f));
            }
        }
        __syncthreads();
        const int og = t & 15, ng = t >> 4;
        float4 s = z4;
        #pragma unroll
        for (int j = 0; j < 4; ++j) {
            int node = i0 + ng * 4 + j;
            if (node < N_API) {
                ushort4 v = *reinterpret_cast<const ushort4*>(Xb + (ng * 4 + j) * 64 + og * 4);
                *reinterpret_cast<ushort4*>(ha_new + (size_t)node * H + og * 4) = v;
                if (psh) addb(s, v);
            }
        }
        if (psh) {
            __syncthreads();
            float4* X4 = reinterpret_cast<float4*>(Xb);
            X4[ng * 16 + og] = s;
            __syncthreads();
            if (ng == 0) {
                float4 tot = z4;
                #pragma unroll
                for (int q = 0; q < 16; ++q) add4(tot, X4[q * 16 + og]);
                float* dst = psh + (size_t)(b & (NSHADOW - 1)) * 128 + 64 + og * 4;
                atomicAdd(dst + 0, tot.x); atomicAdd(dst + 1, tot.y);
                atomicAdd(dst + 2, tot.z); atomicAdd(dst + 3, tot.w);
            }
        }
    }
}

__global__ __launch_bounds__(128) void classifier_kernel(const float* __restrict__ shadows,
        const float* __restrict__ Wc1, const float* __restrict__ bc1,
        const float* __restrict__ Wc2, const float* __restrict__ bc2,
        float* __restrict__ out)
{
    __shared__ float ps[128];
    __shared__ float z1[64];
    int t = threadIdx.x;
    float s = 0.f;
    for (int q = 0; q < NSHADOW; ++q) s += shadows[q * 128 + t];
    ps[t] = s * (t < 64 ? (1.0f / N_FUNC) : (1.0f / N_API));
    __syncthreads();
    if (t < 64) {
        float a = bc1[t];
        for (int k = 0; k < 128; ++k) a = fmaf(ps[k], Wc1[t * 128 + k], a);
        z1[t] = fmaxf(a, 0.f);
    }
    __syncthreads();
    if (t < 2) {
        float a = bc2[t];
        for (int j = 0; j < 64; ++j) a = fmaf(z1[j], Wc2[t * 64 + j], a);
        out[t] = a;
    }
}

extern "C" void kernel_launch(void* const* d_in, const int* in_sizes, int n_in,
                              void* d_out, int out_size, void* d_ws, size_t ws_size,
                              hipStream_t stream)
{
    const float* x_func    = (const float*)d_in[0];
    const float* x_api     = (const float*)d_in[1];
    const float* w_in_func = (const float*)d_in[2];
    const float* b_in_func = (const float*)d_in[3];
    const float* w_in_api  = (const float*)d_in[4];
    const float* b_in_api  = (const float*)d_in[5];
    const float* Wl_calls  = (const float*)d_in[6];
    const float* bl_calls  = (const float*)d_in[7];
    const float* Wr_calls  = (const float*)d_in[8];
    const float* Wl_uses   = (const float*)d_in[9];
    const float* bl_uses   = (const float*)d_in[10];
    const float* Wr_uses   = (const float*)d_in[11];
    const float* Wl_usedby = (const float*)d_in[12];
    const float* bl_usedby = (const float*)d_in[13];
    const float* Wr_usedby = (const float*)d_in[14];
    const float* Wc1       = (const float*)d_in[15];
    const float* bc1       = (const float*)d_in[16];
    const float* Wc2       = (const float*)d_in[17];
    const float* bc2       = (const float*)d_in[18];
    const int*   ei_calls  = (const int*)d_in[19];
    const int*   ei_uses   = (const int*)d_in[20];
    const int*   ei_usedby = (const int*)d_in[21];
    const int E = in_sizes[19] / 2;

    float* ws = (float*)d_ws;
    size_t off = 0;
    u16* hf0 = (u16*)(ws + off); off += (size_t)N_FUNC * 32;
    u16* hf1 = (u16*)(ws + off); off += (size_t)N_FUNC * 32;
    u16* ha0 = (u16*)(ws + off); off += (size_t)N_API * 32;
    u16* ha1 = (u16*)(ws + off); off += (size_t)N_API * 32;
    u16* wpk = (u16*)(ws + off); off += 53248;   // 106496 u16 packed weights
    int* bktC = (int*)(ws + off); off += NBK;
    int* bktU = (int*)(ws + off); off += NBK;
    int* bktA = (int*)(ws + off); off += NBK;
    float* shadows = ws + off; off += NSHADOW * 128;
    int* bbC = (int*)(ws + off); off += NBK;
    int* bbU = (int*)(ws + off); off += NBK;
    int* bbA = (int*)(ws + off); off += NBK;
    int* rpC = (int*)(ws + off); off += N_FUNC + 1;
    int* rpU = (int*)(ws + off); off += N_FUNC + 1;
    int* rpA = (int*)(ws + off); off += N_API + 1;
    int* colC = (int*)(ws + off); off += E;
    int* colU = (int*)(ws + off); off += E;
    int* colA = (int*)(ws + off); off += E;
    int* beC = (int*)(ws + off); off += (size_t)NBK * BCAP;
    int* beU = (int*)(ws + off); off += (size_t)NBK * BCAP;
    int* beA = (int*)(ws + off); off += (size_t)NBK * BCAP;

    const int nbPerRel = (E + EPB - 1) / EPB;

    hipMemsetAsync(bktC, 0, (size_t)(3 * NBK + NSHADOW * 128) * sizeof(float), stream);

    prep_and_binA<<<PREPB + 3 * nbPerRel, 256, 0, stream>>>(
            w_in_func, w_in_api, Wl_calls, Wr_calls, Wl_uses, Wr_uses,
            Wl_usedby, Wr_usedby, wpk,
            ei_calls, ei_calls + E, ei_usedby, ei_usedby + E, ei_uses, ei_uses + E,
            bktC, bktU, bktA, beC, beU, beA, E, nbPerRel);

    scan_buckets<<<1, 256, 0, stream>>>(bktC, bktU, bktA, bbC, bbU, bbA);

    u16* wpkf = wpk;
    u16* wpka = wpk + 16384;
    u16* wpkL = wpk + 24576;
    u16 *pk_r[NLAYERS], *pk_lc[NLAYERS], *pk_lu[NLAYERS], *pk_luse[NLAYERS], *pk_ruse[NLAYERS];
    for (int l = 0; l < NLAYERS; ++l) {
        pk_r[l]    = wpkL + (size_t)(l * 5 + 0) * 8192;
        pk_lc[l]   = wpkL + (size_t)(l * 5 + 1) * 8192;
        pk_lu[l]   = wpkL + (size_t)(l * 5 + 2) * 8192;
        pk_luse[l] = wpkL + (size_t)(l * 5 + 3) * 8192;
        pk_ruse[l] = wpkL + (size_t)(l * 5 + 4) * 8192;
    }

    binB_and_proj<<<3 * NBK + NBF + NBA, 256, 0, stream>>>(
            beC, beU, beA, bktC, bktU, bktA, bbC, bbU, bbA,
            rpC, rpU, rpA, colC, colU, colA,
            x_func, wpkf, b_in_func, hf0,
            x_api, wpka, b_in_api, ha0);

    u16* hf[2] = { hf0, hf1 };
    u16* ha[2] = { ha0, ha1 };
    for (int l = 0; l < NLAYERS; ++l) {
        int cur = l & 1, nxt = cur ^ 1;
        layer_both<<<NBF + NBA, 256, 0, stream>>>(
                hf[cur], ha[cur], hf[nxt], ha[nxt],
                rpC, colC, rpU, colU, rpA, colA,
                pk_r[l], pk_lc[l], pk_lu[l], pk_ruse[l], pk_luse[l],
                bl_calls + l * 64, bl_usedby + l * 64, bl_uses + l * 64,
                (l == NLAYERS - 1) ? shadows : nullptr);
    }

    classifier_kernel<<<1, 128, 0, stream>>>(shadows, Wc1, bc1, Wc2, bc2, (float*)d_out);
}